// Round 9
// baseline (2347.937 us; speedup 1.0000x reference)
//
#include <hip/hip_runtime.h>
#include <math.h>

#define BB   2048
#define NN_  768
#define MM   3072
#define LAMBD 0.1f

typedef __attribute__((ext_vector_type(8))) _Float16 half8;
typedef __attribute__((ext_vector_type(4))) float  f32x4;
typedef __attribute__((ext_vector_type(4))) unsigned short us4;

union HB { _Float16 f; unsigned short u; };
struct HL { unsigned short h, l; };

__device__ __forceinline__ unsigned short h_bits(float f) {
    HB b; b.f = (_Float16)f; return b.u;
}
__device__ __forceinline__ HL split2h(float f) {
    HL r;
    HB b; b.f = (_Float16)f;
    r.h = b.u;
    const float fh = (float)b.f;
    HB c; c.f = (_Float16)(f - fh);
    r.l = c.u;
    return r;
}
__device__ __forceinline__ float clampl(float x) {
    return fminf(fmaxf(x, -LAMBD), LAMBD);
}

// ---------------------------------------------------------------------------
// Split-K small GEMM (768x768 out, fp16 3-term), 64x64 tile, reg-prefetch +
// LDS double-buffer (one barrier per K-step). Grid: (12, 12, KS).
// ---------------------------------------------------------------------------
template<int APRE>
__global__ __launch_bounds__(256)
void gemm_sk(const float* __restrict__ A,
             const unsigned short* __restrict__ Ah,
             const unsigned short* __restrict__ Al,
             int lda,
             const unsigned short* __restrict__ Bh,
             const unsigned short* __restrict__ Bl,
             int ldb,
             float* __restrict__ P, int Kper)
{
    __shared__ unsigned short AsH[2][64][40], AsL[2][64][40];
    __shared__ unsigned short BsH[2][64][40], BsL[2][64][40];

    const int tid  = threadIdx.x;
    const int brow = blockIdx.y * 64;
    const int bcol = blockIdx.x * 64;
    const int koff = blockIdx.z * Kper;
    const int wave = tid >> 6, lane = tid & 63;
    const int wr = wave >> 1, wc = wave & 1;
    const int lrow = lane & 15, kg = lane >> 4;

    const int sk4  = (tid & 7) << 2;

    us4   rAh[2], rAl[2], rBh[2], rBl[2];
    float4 rAf[2];

    auto LOAD = [&](int k0) {
        #pragma unroll
        for (int p = 0; p < 2; ++p) {
            const int row = (p * 256 + tid) >> 3;
            const size_t ga = (size_t)(brow + row) * lda + k0 + sk4;
            const size_t gb = (size_t)(bcol + row) * ldb + k0 + sk4;
            if constexpr (APRE) {
                rAh[p] = *(const us4*)(Ah + ga);
                rAl[p] = *(const us4*)(Al + ga);
            } else {
                rAf[p] = *(const float4*)(A + ga);
            }
            rBh[p] = *(const us4*)(Bh + gb);
            rBl[p] = *(const us4*)(Bl + gb);
        }
    };
    auto STORE = [&](int b) {
        #pragma unroll
        for (int p = 0; p < 2; ++p) {
            const int row = (p * 256 + tid) >> 3;
            if constexpr (APRE) {
                *(us4*)&AsH[b][row][sk4] = rAh[p];
                *(us4*)&AsL[b][row][sk4] = rAl[p];
            } else {
                const HL sx = split2h(rAf[p].x), sy = split2h(rAf[p].y);
                const HL sz = split2h(rAf[p].z), sw = split2h(rAf[p].w);
                us4 h, l;
                h.x = sx.h; l.x = sx.l; h.y = sy.h; l.y = sy.l;
                h.z = sz.h; l.z = sz.l; h.w = sw.h; l.w = sw.l;
                *(us4*)&AsH[b][row][sk4] = h;
                *(us4*)&AsL[b][row][sk4] = l;
            }
            *(us4*)&BsH[b][row][sk4] = rBh[p];
            *(us4*)&BsL[b][row][sk4] = rBl[p];
        }
    };

    f32x4 acc[2][2];
    #pragma unroll
    for (int m = 0; m < 2; ++m)
        #pragma unroll
        for (int n = 0; n < 2; ++n)
            #pragma unroll
            for (int q = 0; q < 4; ++q) acc[m][n][q] = 0.0f;

    const int NK = Kper / 32;
    LOAD(koff);
    STORE(0);
    __syncthreads();

    int cur = 0;
    for (int ki = 0; ki < NK; ++ki) {
        if (ki + 1 < NK) LOAD(koff + (ki + 1) * 32);

        half8 ahi[2], alo[2], bhi[2], blo[2];
        #pragma unroll
        for (int m = 0; m < 2; ++m) {
            const int r = wr * 32 + m * 16 + lrow;
            ahi[m] = *(const half8*)&AsH[cur][r][kg * 8];
            alo[m] = *(const half8*)&AsL[cur][r][kg * 8];
        }
        #pragma unroll
        for (int n = 0; n < 2; ++n) {
            const int c = wc * 32 + n * 16 + lrow;
            bhi[n] = *(const half8*)&BsH[cur][c][kg * 8];
            blo[n] = *(const half8*)&BsL[cur][c][kg * 8];
        }
        #pragma unroll
        for (int m = 0; m < 2; ++m)
            #pragma unroll
            for (int n = 0; n < 2; ++n) {
                acc[m][n] = __builtin_amdgcn_mfma_f32_16x16x32_f16(ahi[m], bhi[n], acc[m][n], 0, 0, 0);
                acc[m][n] = __builtin_amdgcn_mfma_f32_16x16x32_f16(ahi[m], blo[n], acc[m][n], 0, 0, 0);
                acc[m][n] = __builtin_amdgcn_mfma_f32_16x16x32_f16(alo[m], bhi[n], acc[m][n], 0, 0, 0);
            }
        if (ki + 1 < NK) STORE(cur ^ 1);
        __syncthreads();
        cur ^= 1;
    }

    float* Pk = P + (size_t)blockIdx.z * NN_ * NN_;
    #pragma unroll
    for (int m = 0; m < 2; ++m)
        #pragma unroll
        for (int n = 0; n < 2; ++n)
            #pragma unroll
            for (int r = 0; r < 4; ++r) {
                const int row = brow + wr * 32 + m * 16 + kg * 4 + r;
                const int col = bcol + wc * 32 + n * 16 + lrow;
                Pk[(size_t)row * NN_ + col] = acc[m][n][r];
            }
}

// Reduce 4 split-K partials with epilogue. MODE: 0 plain, 1 +I, 2 2*E1-sum.
template<int MODE>
__global__ __launch_bounds__(256)
void red_ns(const float* __restrict__ P,
            const float* __restrict__ E1,
            float* __restrict__ C,
            unsigned short* __restrict__ Ch,
            unsigned short* __restrict__ Cl)
{
    const size_t i4 = ((size_t)blockIdx.x * 256 + threadIdx.x) * 4;
    const size_t sz = (size_t)NN_ * NN_;
    float4 s = *(const float4*)(P + i4);
    const float4 s1 = *(const float4*)(P + sz + i4);
    const float4 s2 = *(const float4*)(P + 2 * sz + i4);
    const float4 s3 = *(const float4*)(P + 3 * sz + i4);
    s.x = (s.x + s1.x) + (s2.x + s3.x);
    s.y = (s.y + s1.y) + (s2.y + s3.y);
    s.z = (s.z + s1.z) + (s2.z + s3.z);
    s.w = (s.w + s1.w) + (s2.w + s3.w);
    float v[4] = {s.x, s.y, s.z, s.w};
    if constexpr (MODE == 1) {
        const int row = (int)(i4 / NN_);
        const int col = (int)(i4 - (size_t)row * NN_);
        #pragma unroll
        for (int j = 0; j < 4; ++j) if (row == col + j) v[j] += 1.0f;
    }
    if constexpr (MODE == 2) {
        const float4 e = *(const float4*)(E1 + i4);
        v[0] = 2.0f * e.x - v[0]; v[1] = 2.0f * e.y - v[1];
        v[2] = 2.0f * e.z - v[2]; v[3] = 2.0f * e.w - v[3];
    }
    float4 o; o.x = v[0]; o.y = v[1]; o.z = v[2]; o.w = v[3];
    *(float4*)(C + i4) = o;
    us4 h, l;
    const HL a = split2h(v[0]), b = split2h(v[1]);
    const HL c = split2h(v[2]), d = split2h(v[3]);
    h.x = a.h; l.x = a.l; h.y = b.h; l.y = b.l;
    h.z = c.h; l.z = c.l; h.w = d.h; l.w = d.l;
    *(us4*)(Ch + i4) = h;
    *(us4*)(Cl + i4) = l;
}

// ---------------------------------------------------------------------------
// Big fp16 2-term GEMM: 64x64 tile, 4 waves (32x32 each), BK=32, reg-prefetch
// + LDS double-buffer (one barrier per K-step).
// A: staged fp16 hi only. B: pre-split fp16 h/l read as [col][k].
// AMODE: 0 = f32 A; 1 = pre-cvt fp16 (Ah); 3 = f32 A + A[psz] partial sum.
// EPI: 0 = C[cks*ks+idx]=acc (+EMIT); 3 = ADMM w-update (y2 emit / LASTZ->z).
// EMIT: 0 none, 1 Y2=fp16(acc), 2 EH/EL = split fp16(acc).
// Grid: flat NBM*NBN*KS; per-XCD 2D patch PM x PN (x 1 ks-slice) for L2 reuse.
// ---------------------------------------------------------------------------
template<int NBM, int NBN, int KS, int PM, int PN, int AMODE, int EPI, int EMIT, int LASTZ>
__global__ __launch_bounds__(256)
void gemm_big(const float* __restrict__ A,
              const unsigned short* __restrict__ Ah,
              int lda, size_t psz,
              const unsigned short* __restrict__ Bh,
              const unsigned short* __restrict__ Bl,
              int ldb,
              float* __restrict__ C, int ldc, size_t cks, int Kper,
              const float* __restrict__ F1,
              float* __restrict__ Wio,
              float* __restrict__ OutZ,
              unsigned short* __restrict__ Y2,
              unsigned short* __restrict__ EH,
              unsigned short* __restrict__ EL)
{
    static_assert(NBM % PM == 0 && NBN % PN == 0, "patch divides grid");
    constexpr int XM = NBM / PM, XN = NBN / PN;
    static_assert(XM * XN * KS == 8, "patches x KS must equal 8 XCDs");
    static_assert(PM * PN == (NBM * NBN * KS) / 8, "slot count");

    __shared__ unsigned short AsH[2][64][40];
    __shared__ unsigned short BsH[2][64][40];
    __shared__ unsigned short BsL[2][64][40];

    const int bid  = blockIdx.x;
    const int xcd  = bid & 7;
    const int slot = bid >> 3;
    const int ks   = xcd % KS;
    const int rest = xcd / KS;
    const int xn   = rest % XN;
    const int xm   = rest / XN;
    const int m_   = xm * PM + slot / PN;
    const int n_   = xn * PN + slot % PN;
    const int brow = m_ * 64;
    const int bcol = n_ * 64;
    const int koff = ks * Kper;

    const int tid  = threadIdx.x;
    const int wave = tid >> 6, lane = tid & 63;
    const int wr = wave >> 1, wc = wave & 1;
    const int lrow = lane & 15, kg = lane >> 4;

    const int srow = tid >> 2, sk8 = (tid & 3) << 3;

    uint4  pA0, pB0, pB1;
    float4 pF[2], pG[2];

    auto LOAD = [&](int k0) {
        const size_t ga = (size_t)(brow + srow) * lda + k0 + sk8;
        if constexpr (AMODE == 1) {
            pA0 = *(const uint4*)(Ah + ga);
        } else {
            pF[0] = *(const float4*)(A + ga);
            pF[1] = *(const float4*)(A + ga + 4);
            if constexpr (AMODE == 3) {
                pG[0] = *(const float4*)(A + ga + psz);
                pG[1] = *(const float4*)(A + ga + psz + 4);
            }
        }
        const size_t gb = (size_t)(bcol + srow) * ldb + k0 + sk8;
        pB0 = *(const uint4*)(Bh + gb);
        pB1 = *(const uint4*)(Bl + gb);
    };
    auto STORE = [&](int b) {
        if constexpr (AMODE == 1) {
            *(uint4*)&AsH[b][srow][sk8] = pA0;
        } else {
            float va[8];
            va[0] = pF[0].x; va[1] = pF[0].y; va[2] = pF[0].z; va[3] = pF[0].w;
            va[4] = pF[1].x; va[5] = pF[1].y; va[6] = pF[1].z; va[7] = pF[1].w;
            if constexpr (AMODE == 3) {
                va[0] += pG[0].x; va[1] += pG[0].y; va[2] += pG[0].z; va[3] += pG[0].w;
                va[4] += pG[1].x; va[5] += pG[1].y; va[6] += pG[1].z; va[7] += pG[1].w;
            }
            half8 h0;
            #pragma unroll
            for (int j = 0; j < 8; ++j) h0[j] = (_Float16)va[j];
            *(half8*)&AsH[b][srow][sk8] = h0;
        }
        *(uint4*)&BsH[b][srow][sk8] = pB0;
        *(uint4*)&BsL[b][srow][sk8] = pB1;
    };

    f32x4 acc[2][2];
    #pragma unroll
    for (int m = 0; m < 2; ++m)
        #pragma unroll
        for (int n = 0; n < 2; ++n)
            #pragma unroll
            for (int q = 0; q < 4; ++q) acc[m][n][q] = 0.0f;

    const int NK = Kper / 32;
    LOAD(koff);
    STORE(0);
    __syncthreads();

    int cur = 0;
    for (int ki = 0; ki < NK; ++ki) {
        if (ki + 1 < NK) LOAD(koff + (ki + 1) * 32);

        half8 ah[2], bh[2], bl[2];
        #pragma unroll
        for (int m = 0; m < 2; ++m)
            ah[m] = *(const half8*)&AsH[cur][wr * 32 + m * 16 + lrow][kg * 8];
        #pragma unroll
        for (int n = 0; n < 2; ++n) {
            const int c = wc * 32 + n * 16 + lrow;
            bh[n] = *(const half8*)&BsH[cur][c][kg * 8];
            bl[n] = *(const half8*)&BsL[cur][c][kg * 8];
        }
        #pragma unroll
        for (int m = 0; m < 2; ++m)
            #pragma unroll
            for (int n = 0; n < 2; ++n) {
                acc[m][n] = __builtin_amdgcn_mfma_f32_16x16x32_f16(ah[m], bh[n], acc[m][n], 0, 0, 0);
                acc[m][n] = __builtin_amdgcn_mfma_f32_16x16x32_f16(ah[m], bl[n], acc[m][n], 0, 0, 0);
            }
        if (ki + 1 < NK) STORE(cur ^ 1);
        __syncthreads();
        cur ^= 1;
    }

    #pragma unroll
    for (int m = 0; m < 2; ++m) {
        #pragma unroll
        for (int n = 0; n < 2; ++n) {
            #pragma unroll
            for (int r = 0; r < 4; ++r) {
                const int row = brow + wr * 32 + m * 16 + kg * 4 + r;
                const int col = bcol + wc * 32 + n * 16 + lrow;
                const size_t idx = (size_t)row * ldc + col;
                const float v = acc[m][n][r];
                if constexpr (EPI == 0) {
                    C[cks * ks + idx] = v;
                    if constexpr (EMIT == 1) Y2[idx] = h_bits(v);
                    if constexpr (EMIT == 2) {
                        const HL s = split2h(v);
                        EH[idx] = s.h; EL[idx] = s.l;
                    }
                } else { // EPI == 3: ADMM w-update
                    const float ww  = Wio[idx];
                    const float wn_ = F1[idx] + ww - clampl(ww) - v;
                    if constexpr (LASTZ) {
                        OutZ[idx] = wn_ - clampl(wn_);
                    } else {
                        Wio[idx] = wn_;
                        Y2[idx]  = h_bits(F1[idx] + wn_ - 2.0f * clampl(wn_));
                    }
                }
            }
        }
    }
}

// Normalize rows of weight (3072x768); emit fp16 h/l of wn and wn^T.
__global__ __launch_bounds__(256)
void rownorm_kernel(const float* __restrict__ W,
                    unsigned short* __restrict__ wnH, unsigned short* __restrict__ wnL,
                    unsigned short* __restrict__ wnTH, unsigned short* __restrict__ wnTL)
{
    __shared__ float red[256];
    const int row = blockIdx.x;
    const int t = threadIdx.x;
    const float* wr = W + (size_t)row * NN_;
    float s = 0.0f;
    for (int k = t; k < NN_; k += 256) { const float w = wr[k]; s += w * w; }
    red[t] = s; __syncthreads();
    for (int off = 128; off > 0; off >>= 1) {
        if (t < off) red[t] += red[t + off];
        __syncthreads();
    }
    const float rn = 1.0f / sqrtf(red[0]);
    for (int k = t; k < NN_; k += 256) {
        const float v = wr[k] * rn;
        const HL s2 = split2h(v);
        wnH[(size_t)row * NN_ + k] = s2.h;
        wnL[(size_t)row * NN_ + k] = s2.l;
        wnTH[(size_t)k * MM + row] = s2.h;
        wnTL[(size_t)k * MM + row] = s2.l;
    }
}

__global__ __launch_bounds__(256)
void rowabs_kernel(const float* __restrict__ G, float* __restrict__ rowsum)
{
    __shared__ float red[256];
    const int row = blockIdx.x;
    const int t = threadIdx.x;
    const float* gr = G + (size_t)row * NN_;
    float s = 0.0f;
    for (int k = t; k < NN_; k += 256) s += fabsf(gr[k]);
    red[t] = s; __syncthreads();
    for (int off = 128; off > 0; off >>= 1) {
        if (t < off) red[t] += red[t + off];
        __syncthreads();
    }
    if (t == 0) rowsum[row] = red[0];
}

__global__ __launch_bounds__(256)
void cmax_kernel(const float* __restrict__ rowsum, float* __restrict__ cbuf)
{
    __shared__ float red[256];
    const int t = threadIdx.x;
    float mx = 0.0f;
    for (int k = t; k < NN_; k += 256) mx = fmaxf(mx, rowsum[k]);
    red[t] = mx; __syncthreads();
    for (int off = 128; off > 0; off >>= 1) {
        if (t < off) red[t] = fmaxf(red[t], red[t + off]);
        __syncthreads();
    }
    if (t == 0) cbuf[0] = 2.0f / (1.0f + red[0]);
}

__global__ __launch_bounds__(256)
void initdiag_kernel(float* __restrict__ X, const float* __restrict__ c)
{
    const int idx = blockIdx.x * 256 + threadIdx.x;
    const int p = idx / NN_, q = idx - p * NN_;
    X[idx] = (p == q) ? c[0] : 0.0f;
}

// dec = p0 + p1 (float4)
__global__ __launch_bounds__(256)
void add2_kernel(const float* __restrict__ p0, size_t ps, float* __restrict__ o)
{
    const size_t i = ((size_t)blockIdx.x * 256 + threadIdx.x) * 4;
    const float4 a = *(const float4*)(p0 + i);
    const float4 b = *(const float4*)(p0 + ps + i);
    float4 v;
    v.x = a.x + b.x; v.y = a.y + b.y;
    v.z = a.z + b.z; v.w = a.w + b.w;
    *(float4*)(o + i) = v;
}

extern "C" void kernel_launch(void* const* d_in, const int* in_sizes, int n_in,
                              void* d_out, int out_size, void* d_ws, size_t ws_size,
                              hipStream_t stream)
{
    const float* x = (const float*)d_in[0];   // (2048, 768)
    const float* w = (const float*)d_in[1];   // (3072, 768)

    float* out = (float*)d_out;
    float* z   = out;                          // (2048, 3072)
    float* dec = out + (size_t)BB * MM;        // (2048, 768)

    char* wsb = (char*)d_ws;
    size_t off = 0;
    auto alloc = [&](size_t bytes) -> void* {
        void* p = wsb + off;
        off += (bytes + 255) & ~(size_t)255;
        return p;
    };
    // --- persistent ---
    unsigned short* wnH  = (unsigned short*)alloc((size_t)MM * NN_ * 2);
    unsigned short* wnL  = (unsigned short*)alloc((size_t)MM * NN_ * 2);
    unsigned short* wnTH = (unsigned short*)alloc((size_t)MM * NN_ * 2);
    unsigned short* wnTL = (unsigned short*)alloc((size_t)MM * NN_ * 2);
    float* adotb = (float*)alloc((size_t)BB * MM * 4);
    float* wbuf  = (float*)alloc((size_t)BB * MM * 4);
    unsigned short* y2h = (unsigned short*)alloc((size_t)BB * MM * 2);
    unsigned short* QH  = (unsigned short*)alloc((size_t)NN_ * NN_ * 2);
    unsigned short* QL  = (unsigned short*)alloc((size_t)NN_ * NN_ * 2);
    unsigned short* RTH = (unsigned short*)alloc((size_t)MM * NN_ * 2);
    unsigned short* RTL = (unsigned short*)alloc((size_t)MM * NN_ * 2);
    // --- overlay: NS temps (dead after RT) aliased with T/dec partials ---
    const size_t overlay = off;
    float* G  = (float*)alloc((size_t)NN_ * NN_ * 4);
    unsigned short* GH  = (unsigned short*)alloc((size_t)NN_ * NN_ * 2);
    unsigned short* GL  = (unsigned short*)alloc((size_t)NN_ * NN_ * 2);
    float* X0 = (float*)alloc((size_t)NN_ * NN_ * 4);
    float* X1 = (float*)alloc((size_t)NN_ * NN_ * 4);
    float* Yb = (float*)alloc((size_t)NN_ * NN_ * 4);
    unsigned short* YbH = (unsigned short*)alloc((size_t)NN_ * NN_ * 2);
    unsigned short* YbL = (unsigned short*)alloc((size_t)NN_ * NN_ * 2);
    float* rowsum = (float*)alloc(NN_ * 4);
    float* cbuf   = (float*)alloc(256);
    float* Pp = (float*)alloc((size_t)4 * NN_ * NN_ * 4);  // split-K partials
    // Tp (2 x 2048x768 f32 = 12.6 MB) aliases the NS-temp region (~14.2 MB);
    // NS temps are dead before first Tp use (RT GEMM). Pp is NOT aliased.
    float* Tp = (float*)(wsb + overlay);
    const size_t TPS = (size_t)BB * NN_;

    (void)hipMemsetAsync(wbuf, 0, (size_t)BB * MM * sizeof(float), stream);

    const dim3 blk(256);
    const dim3 gsk(NN_ / 64, NN_ / 64, 4);
    const int  RED = (NN_ * NN_ / 4) / 256;   // 576

    rownorm_kernel<<<MM, blk, 0, stream>>>(w, wnH, wnL, wnTH, wnTL);

    // adotb = x @ wn^T (M2048 N3072 K768); emit y2_0 = fp16(adotb)
    gemm_big<32,48,1,8,24,0,0,1,0><<<1536, blk, 0, stream>>>(
        x, nullptr, NN_, 0, wnH, wnL, NN_, adotb, MM, 0, NN_,
        nullptr, nullptr, nullptr, y2h, nullptr, nullptr);

    // G = wn^T wn + I (768x768, K=3072), split-K=4 + reduce(+I, split)
    gemm_sk<1><<<gsk, blk, 0, stream>>>(
        nullptr, wnTH, wnTL, MM, wnTH, wnTL, MM, Pp, MM / 4);
    red_ns<1><<<RED, blk, 0, stream>>>(Pp, nullptr, G, GH, GL);

    rowabs_kernel<<<NN_, blk, 0, stream>>>(G, rowsum);
    cmax_kernel<<<1, blk, 0, stream>>>(rowsum, cbuf);
    initdiag_kernel<<<(NN_ * NN_) / 256, blk, 0, stream>>>(X0, cbuf);

    // Newton-Schulz X <- 2X - XGX, 7 iterations, split-K=4 per GEMM
    float* Xc = X0;
    float* Xn = X1;
    for (int it = 0; it < 7; ++it) {
        gemm_sk<0><<<gsk, blk, 0, stream>>>(
            Xc, nullptr, nullptr, NN_, GH, GL, NN_, Pp, NN_ / 4);
        red_ns<0><<<RED, blk, 0, stream>>>(Pp, nullptr, Yb, YbH, YbL);
        gemm_sk<0><<<gsk, blk, 0, stream>>>(
            Xc, nullptr, nullptr, NN_, YbH, YbL, NN_, Pp, NN_ / 4);
        red_ns<2><<<RED, blk, 0, stream>>>(Pp, Xc, Xn, QH, QL);
        float* t = Xc; Xc = Xn; Xn = t;
    }
    // QH/QL = fp16 split of G^{-1}

    // RT = wn @ Ginv (M3072 N768 K768); emit RTH/RTL (f32 copy to Tp scratch)
    gemm_big<48,12,1,12,6,1,0,2,0><<<576, blk, 0, stream>>>(
        nullptr, wnH, NN_, 0, QH, QL, NN_, Tp, NN_, 0, NN_,
        nullptr, nullptr, nullptr, nullptr, RTH, RTL);

    // ADMM loop: T = y2 @ wn (KS=2 partials); w-update consumes partial sum
    for (int it = 0; it < 20; ++it) {
        gemm_big<32,12,2,16,6,1,0,0,0><<<768, blk, 0, stream>>>(
            nullptr, y2h, MM, 0, wnTH, wnTL, MM, Tp, NN_, TPS, MM / 2,
            nullptr, nullptr, nullptr, nullptr, nullptr, nullptr);
        if (it < 19) {
            gemm_big<32,48,1,8,24,3,3,0,0><<<1536, blk, 0, stream>>>(
                Tp, nullptr, NN_, TPS, RTH, RTL, NN_, nullptr, MM, 0, NN_,
                adotb, wbuf, nullptr, y2h, nullptr, nullptr);
        } else {
            gemm_big<32,48,1,8,24,3,3,0,1><<<1536, blk, 0, stream>>>(
                Tp, nullptr, NN_, TPS, RTH, RTL, NN_, nullptr, MM, 0, NN_,
                adotb, wbuf, z, nullptr, nullptr, nullptr);
        }
    }

    // decoded = z @ wn (M2048 N768 K3072), KS=2 partials + reduce
    gemm_big<32,12,2,16,6,0,0,0,0><<<768, blk, 0, stream>>>(
        z, nullptr, MM, 0, wnTH, wnTL, MM, Tp, NN_, TPS, MM / 2,
        nullptr, nullptr, nullptr, nullptr, nullptr, nullptr);
    add2_kernel<<<(BB * NN_ / 4) / 256, blk, 0, stream>>>(Tp, TPS, dec);
}

// Round 10
// 2301.006 us; speedup vs baseline: 1.0204x; 1.0204x over previous
//
#include <hip/hip_runtime.h>
#include <math.h>

#define BB   2048
#define NN_  768
#define MM   3072
#define LAMBD 0.1f

typedef __attribute__((ext_vector_type(8))) _Float16 half8;
typedef __attribute__((ext_vector_type(4))) float  f32x4;
typedef __attribute__((ext_vector_type(4))) unsigned short us4;

union HB { _Float16 f; unsigned short u; };
struct HL { unsigned short h, l; };

__device__ __forceinline__ unsigned short h_bits(float f) {
    HB b; b.f = (_Float16)f; return b.u;
}
__device__ __forceinline__ HL split2h(float f) {
    HL r;
    HB b; b.f = (_Float16)f;
    r.h = b.u;
    const float fh = (float)b.f;
    HB c; c.f = (_Float16)(f - fh);
    r.l = c.u;
    return r;
}
__device__ __forceinline__ float clampl(float x) {
    return fminf(fmaxf(x, -LAMBD), LAMBD);
}

// lgkmcnt(0) + raw barrier: own LDS writes drained, global loads stay in flight
#define LGKMBAR() do {                                          \
    asm volatile("s_waitcnt lgkmcnt(0)" ::: "memory");          \
    __builtin_amdgcn_sched_barrier(0);                          \
    __builtin_amdgcn_s_barrier();                               \
} while (0)

// ---------------------------------------------------------------------------
// Split-K small GEMM (768x768 out, fp16 3-term), 64x64 tile, reg-prefetch,
// single LDS buffer (R8-proven). Grid: (12, 12, KS).
// ---------------------------------------------------------------------------
template<int APRE>
__global__ __launch_bounds__(256)
void gemm_sk(const float* __restrict__ A,
             const unsigned short* __restrict__ Ah,
             const unsigned short* __restrict__ Al,
             int lda,
             const unsigned short* __restrict__ Bh,
             const unsigned short* __restrict__ Bl,
             int ldb,
             float* __restrict__ P, int Kper)
{
    __shared__ unsigned short AsH[64][40], AsL[64][40];
    __shared__ unsigned short BsH[64][40], BsL[64][40];

    const int tid  = threadIdx.x;
    const int brow = blockIdx.y * 64;
    const int bcol = blockIdx.x * 64;
    const int koff = blockIdx.z * Kper;
    const int wave = tid >> 6, lane = tid & 63;
    const int wr = wave >> 1, wc = wave & 1;
    const int lrow = lane & 15, kg = lane >> 4;

    const int sk4  = (tid & 7) << 2;

    us4   rAh[2], rAl[2], rBh[2], rBl[2];
    float4 rAf[2];

    auto LOAD = [&](int k0) {
        #pragma unroll
        for (int p = 0; p < 2; ++p) {
            const int row = (p * 256 + tid) >> 3;
            const size_t ga = (size_t)(brow + row) * lda + k0 + sk4;
            const size_t gb = (size_t)(bcol + row) * ldb + k0 + sk4;
            if constexpr (APRE) {
                rAh[p] = *(const us4*)(Ah + ga);
                rAl[p] = *(const us4*)(Al + ga);
            } else {
                rAf[p] = *(const float4*)(A + ga);
            }
            rBh[p] = *(const us4*)(Bh + gb);
            rBl[p] = *(const us4*)(Bl + gb);
        }
    };
    auto STORE = [&]() {
        #pragma unroll
        for (int p = 0; p < 2; ++p) {
            const int row = (p * 256 + tid) >> 3;
            if constexpr (APRE) {
                *(us4*)&AsH[row][sk4] = rAh[p];
                *(us4*)&AsL[row][sk4] = rAl[p];
            } else {
                const HL sx = split2h(rAf[p].x), sy = split2h(rAf[p].y);
                const HL sz = split2h(rAf[p].z), sw = split2h(rAf[p].w);
                us4 h, l;
                h.x = sx.h; l.x = sx.l; h.y = sy.h; l.y = sy.l;
                h.z = sz.h; l.z = sz.l; h.w = sw.h; l.w = sw.l;
                *(us4*)&AsH[row][sk4] = h;
                *(us4*)&AsL[row][sk4] = l;
            }
            *(us4*)&BsH[row][sk4] = rBh[p];
            *(us4*)&BsL[row][sk4] = rBl[p];
        }
    };

    f32x4 acc[2][2];
    #pragma unroll
    for (int m = 0; m < 2; ++m)
        #pragma unroll
        for (int n = 0; n < 2; ++n)
            #pragma unroll
            for (int q = 0; q < 4; ++q) acc[m][n][q] = 0.0f;

    const int NK = Kper / 32;
    LOAD(koff);
    STORE();
    __syncthreads();

    for (int ki = 0; ki < NK; ++ki) {
        if (ki + 1 < NK) LOAD(koff + (ki + 1) * 32);

        half8 ahi[2], alo[2], bhi[2], blo[2];
        #pragma unroll
        for (int m = 0; m < 2; ++m) {
            const int r = wr * 32 + m * 16 + lrow;
            ahi[m] = *(const half8*)&AsH[r][kg * 8];
            alo[m] = *(const half8*)&AsL[r][kg * 8];
        }
        #pragma unroll
        for (int n = 0; n < 2; ++n) {
            const int c = wc * 32 + n * 16 + lrow;
            bhi[n] = *(const half8*)&BsH[c][kg * 8];
            blo[n] = *(const half8*)&BsL[c][kg * 8];
        }
        #pragma unroll
        for (int m = 0; m < 2; ++m)
            #pragma unroll
            for (int n = 0; n < 2; ++n) {
                acc[m][n] = __builtin_amdgcn_mfma_f32_16x16x32_f16(ahi[m], bhi[n], acc[m][n], 0, 0, 0);
                acc[m][n] = __builtin_amdgcn_mfma_f32_16x16x32_f16(ahi[m], blo[n], acc[m][n], 0, 0, 0);
                acc[m][n] = __builtin_amdgcn_mfma_f32_16x16x32_f16(alo[m], bhi[n], acc[m][n], 0, 0, 0);
            }
        __syncthreads();
        if (ki + 1 < NK) { STORE(); __syncthreads(); }
    }

    float* Pk = P + (size_t)blockIdx.z * NN_ * NN_;
    #pragma unroll
    for (int m = 0; m < 2; ++m)
        #pragma unroll
        for (int n = 0; n < 2; ++n)
            #pragma unroll
            for (int r = 0; r < 4; ++r) {
                const int row = brow + wr * 32 + m * 16 + kg * 4 + r;
                const int col = bcol + wc * 32 + n * 16 + lrow;
                Pk[(size_t)row * NN_ + col] = acc[m][n][r];
            }
}

// Reduce 4 split-K partials with epilogue. MODE: 0 plain, 1 +I, 2 2*E1-sum.
template<int MODE>
__global__ __launch_bounds__(256)
void red_ns(const float* __restrict__ P,
            const float* __restrict__ E1,
            float* __restrict__ C,
            unsigned short* __restrict__ Ch,
            unsigned short* __restrict__ Cl)
{
    const size_t i4 = ((size_t)blockIdx.x * 256 + threadIdx.x) * 4;
    const size_t sz = (size_t)NN_ * NN_;
    float4 s = *(const float4*)(P + i4);
    const float4 s1 = *(const float4*)(P + sz + i4);
    const float4 s2 = *(const float4*)(P + 2 * sz + i4);
    const float4 s3 = *(const float4*)(P + 3 * sz + i4);
    s.x = (s.x + s1.x) + (s2.x + s3.x);
    s.y = (s.y + s1.y) + (s2.y + s3.y);
    s.z = (s.z + s1.z) + (s2.z + s3.z);
    s.w = (s.w + s1.w) + (s2.w + s3.w);
    float v[4] = {s.x, s.y, s.z, s.w};
    if constexpr (MODE == 1) {
        const int row = (int)(i4 / NN_);
        const int col = (int)(i4 - (size_t)row * NN_);
        #pragma unroll
        for (int j = 0; j < 4; ++j) if (row == col + j) v[j] += 1.0f;
    }
    if constexpr (MODE == 2) {
        const float4 e = *(const float4*)(E1 + i4);
        v[0] = 2.0f * e.x - v[0]; v[1] = 2.0f * e.y - v[1];
        v[2] = 2.0f * e.z - v[2]; v[3] = 2.0f * e.w - v[3];
    }
    float4 o; o.x = v[0]; o.y = v[1]; o.z = v[2]; o.w = v[3];
    *(float4*)(C + i4) = o;
    us4 h, l;
    const HL a = split2h(v[0]), b = split2h(v[1]);
    const HL c = split2h(v[2]), d = split2h(v[3]);
    h.x = a.h; l.x = a.l; h.y = b.h; l.y = b.l;
    h.z = c.h; l.z = c.l; h.w = d.h; l.w = d.l;
    *(us4*)(Ch + i4) = h;
    *(us4*)(Cl + i4) = l;
}

// ---------------------------------------------------------------------------
// Big fp16 2-term GEMM: 64x64 tile, 4 waves (32x32), BK=32.
// Depth-2 register pipeline + LDS double-buffer + RAW s_barrier (no vmcnt
// drain): LOAD(t+2) issued at step t; STORE(t+1) consumes the set loaded at
// t-1 -> compiler emits counted vmcnt, loads span 2 compute phases.
// EPI==3 additionally prefetches the epilogue streams (adotb/wbuf) in the
// prologue (T14: issue-early, use-late).
// AMODE: 0 = f32 A; 1 = pre-cvt fp16 (Ah); 3 = f32 A + A[psz] partial sum.
// EPI: 0 = C[cks*ks+idx]=acc (+EMIT); 3 = ADMM w-update (y2 emit / LASTZ->z).
// EMIT: 0 none, 1 Y2=fp16(acc), 2 EH/EL = split fp16(acc).
// Grid: flat NBM*NBN*KS; per-XCD 2D patch PM x PN for L2 reuse.
// ---------------------------------------------------------------------------
template<int NBM, int NBN, int KS, int PM, int PN, int AMODE, int EPI, int EMIT, int LASTZ>
__global__ __launch_bounds__(256)
void gemm_big(const float* __restrict__ A,
              const unsigned short* __restrict__ Ah,
              int lda, size_t psz,
              const unsigned short* __restrict__ Bh,
              const unsigned short* __restrict__ Bl,
              int ldb,
              float* __restrict__ C, int ldc, size_t cks, int Kper,
              const float* __restrict__ F1,
              float* __restrict__ Wio,
              float* __restrict__ OutZ,
              unsigned short* __restrict__ Y2,
              unsigned short* __restrict__ EH,
              unsigned short* __restrict__ EL)
{
    static_assert(NBM % PM == 0 && NBN % PN == 0, "patch divides grid");
    constexpr int XM = NBM / PM, XN = NBN / PN;
    static_assert(XM * XN * KS == 8, "patches x KS must equal 8 XCDs");
    static_assert(PM * PN == (NBM * NBN * KS) / 8, "slot count");

    __shared__ unsigned short AsH[2][64][40];
    __shared__ unsigned short BsH[2][64][40];
    __shared__ unsigned short BsL[2][64][40];

    const int bid  = blockIdx.x;
    const int xcd  = bid & 7;
    const int slot = bid >> 3;
    const int ks   = xcd % KS;
    const int rest = xcd / KS;
    const int xn   = rest % XN;
    const int xm   = rest / XN;
    const int m_   = xm * PM + slot / PN;
    const int n_   = xn * PN + slot % PN;
    const int brow = m_ * 64;
    const int bcol = n_ * 64;
    const int koff = ks * Kper;

    const int tid  = threadIdx.x;
    const int wave = tid >> 6, lane = tid & 63;
    const int wr = wave >> 1, wc = wave & 1;
    const int lrow = lane & 15, kg = lane >> 4;

    const int srow = tid >> 2, sk8 = (tid & 3) << 3;

    // two register sets (named, static — rule #20)
    uint4  sAa, sAb0, sAb1;  float4 sAf[2], sAg[2];
    uint4  sBa, sBb0, sBb1;  float4 sBf[2], sBg[2];

    auto LOADg = [&](int k0, uint4& rA, float4* rF, float4* rG,
                     uint4& rB0, uint4& rB1) {
        const size_t ga = (size_t)(brow + srow) * lda + k0 + sk8;
        if constexpr (AMODE == 1) {
            rA = *(const uint4*)(Ah + ga);
        } else {
            rF[0] = *(const float4*)(A + ga);
            rF[1] = *(const float4*)(A + ga + 4);
            if constexpr (AMODE == 3) {
                rG[0] = *(const float4*)(A + ga + psz);
                rG[1] = *(const float4*)(A + ga + psz + 4);
            }
        }
        const size_t gb = (size_t)(bcol + srow) * ldb + k0 + sk8;
        rB0 = *(const uint4*)(Bh + gb);
        rB1 = *(const uint4*)(Bl + gb);
    };
    auto STOREg = [&](int b, uint4& rA, float4* rF, float4* rG,
                      uint4& rB0, uint4& rB1) {
        if constexpr (AMODE == 1) {
            *(uint4*)&AsH[b][srow][sk8] = rA;
        } else {
            float va[8];
            va[0] = rF[0].x; va[1] = rF[0].y; va[2] = rF[0].z; va[3] = rF[0].w;
            va[4] = rF[1].x; va[5] = rF[1].y; va[6] = rF[1].z; va[7] = rF[1].w;
            if constexpr (AMODE == 3) {
                va[0] += rG[0].x; va[1] += rG[0].y; va[2] += rG[0].z; va[3] += rG[0].w;
                va[4] += rG[1].x; va[5] += rG[1].y; va[6] += rG[1].z; va[7] += rG[1].w;
            }
            half8 h0;
            #pragma unroll
            for (int j = 0; j < 8; ++j) h0[j] = (_Float16)va[j];
            *(half8*)&AsH[b][srow][sk8] = h0;
        }
        *(uint4*)&BsH[b][srow][sk8] = rB0;
        *(uint4*)&BsL[b][srow][sk8] = rB1;
    };

    f32x4 acc[2][2];
    #pragma unroll
    for (int m = 0; m < 2; ++m)
        #pragma unroll
        for (int n = 0; n < 2; ++n)
            #pragma unroll
            for (int q = 0; q < 4; ++q) acc[m][n][q] = 0.0f;

    auto COMPUTE = [&](int b) {
        half8 ah[2], bh[2], bl[2];
        #pragma unroll
        for (int m = 0; m < 2; ++m)
            ah[m] = *(const half8*)&AsH[b][wr * 32 + m * 16 + lrow][kg * 8];
        #pragma unroll
        for (int n = 0; n < 2; ++n) {
            const int c = wc * 32 + n * 16 + lrow;
            bh[n] = *(const half8*)&BsH[b][c][kg * 8];
            bl[n] = *(const half8*)&BsL[b][c][kg * 8];
        }
        #pragma unroll
        for (int m = 0; m < 2; ++m)
            #pragma unroll
            for (int n = 0; n < 2; ++n) {
                acc[m][n] = __builtin_amdgcn_mfma_f32_16x16x32_f16(ah[m], bh[n], acc[m][n], 0, 0, 0);
                acc[m][n] = __builtin_amdgcn_mfma_f32_16x16x32_f16(ah[m], bl[n], acc[m][n], 0, 0, 0);
            }
    };

    const int NK = Kper / 32;

    // ---- prologue ----
    LOADg(koff, sAa, sAf, sAg, sAb0, sAb1);               // tile 0 -> set A

    // T14: epilogue-stream prefetch (issued after tile-0 loads -> FIFO keeps
    // counted waits usable; retired by the step-0 store wait)
    float pf1[16], pw[16];
    if constexpr (EPI == 3) {
        #pragma unroll
        for (int m = 0; m < 2; ++m)
            #pragma unroll
            for (int n = 0; n < 2; ++n)
                #pragma unroll
                for (int r = 0; r < 4; ++r) {
                    const int row = brow + wr * 32 + m * 16 + kg * 4 + r;
                    const int col = bcol + wc * 32 + n * 16 + lrow;
                    const size_t idx = (size_t)row * ldc + col;
                    pf1[(m * 2 + n) * 4 + r] = F1[idx];
                    pw [(m * 2 + n) * 4 + r] = Wio[idx];
                }
    }

    STOREg(0, sAa, sAf, sAg, sAb0, sAb1);                 // buf0 <- tile 0
    LOADg(koff + 32, sBa, sBf, sBg, sBb0, sBb1);          // tile 1 -> set B
    LGKMBAR();

    // ---- main loop: tile t lives in buf[t%2]; unroll-by-2 ----
    for (int ki = 0; ki < NK; ki += 2) {
        // EVEN step: compute tile ki from buf0
        if (ki + 2 < NK) LOADg(koff + (ki + 2) * 32, sAa, sAf, sAg, sAb0, sAb1);
        COMPUTE(0);
        if (ki + 1 < NK) {
            STOREg(1, sBa, sBf, sBg, sBb0, sBb1);         // tile ki+1 -> buf1
            LGKMBAR();
            // ODD step: compute tile ki+1 from buf1
            if (ki + 3 < NK) LOADg(koff + (ki + 3) * 32, sBa, sBf, sBg, sBb0, sBb1);
            COMPUTE(1);
            if (ki + 2 < NK) {
                STOREg(0, sAa, sAf, sAg, sAb0, sAb1);     // tile ki+2 -> buf0
                LGKMBAR();
            }
        }
    }

    // ---- epilogue ----
    #pragma unroll
    for (int m = 0; m < 2; ++m) {
        #pragma unroll
        for (int n = 0; n < 2; ++n) {
            #pragma unroll
            for (int r = 0; r < 4; ++r) {
                const int row = brow + wr * 32 + m * 16 + kg * 4 + r;
                const int col = bcol + wc * 32 + n * 16 + lrow;
                const size_t idx = (size_t)row * ldc + col;
                const float v = acc[m][n][r];
                if constexpr (EPI == 0) {
                    C[cks * ks + idx] = v;
                    if constexpr (EMIT == 1) Y2[idx] = h_bits(v);
                    if constexpr (EMIT == 2) {
                        const HL s = split2h(v);
                        EH[idx] = s.h; EL[idx] = s.l;
                    }
                } else { // EPI == 3: ADMM w-update (prefetched streams)
                    const float ww  = pw[(m * 2 + n) * 4 + r];
                    const float wn_ = pf1[(m * 2 + n) * 4 + r] + ww - clampl(ww) - v;
                    if constexpr (LASTZ) {
                        OutZ[idx] = wn_ - clampl(wn_);
                    } else {
                        Wio[idx] = wn_;
                        Y2[idx]  = h_bits(pf1[(m * 2 + n) * 4 + r] + wn_ - 2.0f * clampl(wn_));
                    }
                }
            }
        }
    }
}

// Normalize rows of weight (3072x768); emit fp16 h/l of wn and wn^T.
__global__ __launch_bounds__(256)
void rownorm_kernel(const float* __restrict__ W,
                    unsigned short* __restrict__ wnH, unsigned short* __restrict__ wnL,
                    unsigned short* __restrict__ wnTH, unsigned short* __restrict__ wnTL)
{
    __shared__ float red[256];
    const int row = blockIdx.x;
    const int t = threadIdx.x;
    const float* wr = W + (size_t)row * NN_;
    float s = 0.0f;
    for (int k = t; k < NN_; k += 256) { const float w = wr[k]; s += w * w; }
    red[t] = s; __syncthreads();
    for (int off = 128; off > 0; off >>= 1) {
        if (t < off) red[t] += red[t + off];
        __syncthreads();
    }
    const float rn = 1.0f / sqrtf(red[0]);
    for (int k = t; k < NN_; k += 256) {
        const float v = wr[k] * rn;
        const HL s2 = split2h(v);
        wnH[(size_t)row * NN_ + k] = s2.h;
        wnL[(size_t)row * NN_ + k] = s2.l;
        wnTH[(size_t)k * MM + row] = s2.h;
        wnTL[(size_t)k * MM + row] = s2.l;
    }
}

__global__ __launch_bounds__(256)
void rowabs_kernel(const float* __restrict__ G, float* __restrict__ rowsum)
{
    __shared__ float red[256];
    const int row = blockIdx.x;
    const int t = threadIdx.x;
    const float* gr = G + (size_t)row * NN_;
    float s = 0.0f;
    for (int k = t; k < NN_; k += 256) s += fabsf(gr[k]);
    red[t] = s; __syncthreads();
    for (int off = 128; off > 0; off >>= 1) {
        if (t < off) red[t] += red[t + off];
        __syncthreads();
    }
    if (t == 0) rowsum[row] = red[0];
}

__global__ __launch_bounds__(256)
void cmax_kernel(const float* __restrict__ rowsum, float* __restrict__ cbuf)
{
    __shared__ float red[256];
    const int t = threadIdx.x;
    float mx = 0.0f;
    for (int k = t; k < NN_; k += 256) mx = fmaxf(mx, rowsum[k]);
    red[t] = mx; __syncthreads();
    for (int off = 128; off > 0; off >>= 1) {
        if (t < off) red[t] = fmaxf(red[t], red[t + off]);
        __syncthreads();
    }
    if (t == 0) cbuf[0] = 2.0f / (1.0f + red[0]);
}

__global__ __launch_bounds__(256)
void initdiag_kernel(float* __restrict__ X, const float* __restrict__ c)
{
    const int idx = blockIdx.x * 256 + threadIdx.x;
    const int p = idx / NN_, q = idx - p * NN_;
    X[idx] = (p == q) ? c[0] : 0.0f;
}

// dec = p0 + p1 (float4)
__global__ __launch_bounds__(256)
void add2_kernel(const float* __restrict__ p0, size_t ps, float* __restrict__ o)
{
    const size_t i = ((size_t)blockIdx.x * 256 + threadIdx.x) * 4;
    const float4 a = *(const float4*)(p0 + i);
    const float4 b = *(const float4*)(p0 + ps + i);
    float4 v;
    v.x = a.x + b.x; v.y = a.y + b.y;
    v.z = a.z + b.z; v.w = a.w + b.w;
    *(float4*)(o + i) = v;
}

extern "C" void kernel_launch(void* const* d_in, const int* in_sizes, int n_in,
                              void* d_out, int out_size, void* d_ws, size_t ws_size,
                              hipStream_t stream)
{
    const float* x = (const float*)d_in[0];   // (2048, 768)
    const float* w = (const float*)d_in[1];   // (3072, 768)

    float* out = (float*)d_out;
    float* z   = out;                          // (2048, 3072)
    float* dec = out + (size_t)BB * MM;        // (2048, 768)

    char* wsb = (char*)d_ws;
    size_t off = 0;
    auto alloc = [&](size_t bytes) -> void* {
        void* p = wsb + off;
        off += (bytes + 255) & ~(size_t)255;
        return p;
    };
    // --- persistent ---
    unsigned short* wnH  = (unsigned short*)alloc((size_t)MM * NN_ * 2);
    unsigned short* wnL  = (unsigned short*)alloc((size_t)MM * NN_ * 2);
    unsigned short* wnTH = (unsigned short*)alloc((size_t)MM * NN_ * 2);
    unsigned short* wnTL = (unsigned short*)alloc((size_t)MM * NN_ * 2);
    float* adotb = (float*)alloc((size_t)BB * MM * 4);
    float* wbuf  = (float*)alloc((size_t)BB * MM * 4);
    unsigned short* y2h = (unsigned short*)alloc((size_t)BB * MM * 2);
    unsigned short* QH  = (unsigned short*)alloc((size_t)NN_ * NN_ * 2);
    unsigned short* QL  = (unsigned short*)alloc((size_t)NN_ * NN_ * 2);
    unsigned short* RTH = (unsigned short*)alloc((size_t)MM * NN_ * 2);
    unsigned short* RTL = (unsigned short*)alloc((size_t)MM * NN_ * 2);
    // --- overlay: NS temps (dead after RT) aliased with T/dec partials ---
    const size_t overlay = off;
    float* G  = (float*)alloc((size_t)NN_ * NN_ * 4);
    unsigned short* GH  = (unsigned short*)alloc((size_t)NN_ * NN_ * 2);
    unsigned short* GL  = (unsigned short*)alloc((size_t)NN_ * NN_ * 2);
    float* X0 = (float*)alloc((size_t)NN_ * NN_ * 4);
    float* X1 = (float*)alloc((size_t)NN_ * NN_ * 4);
    float* Yb = (float*)alloc((size_t)NN_ * NN_ * 4);
    unsigned short* YbH = (unsigned short*)alloc((size_t)NN_ * NN_ * 2);
    unsigned short* YbL = (unsigned short*)alloc((size_t)NN_ * NN_ * 2);
    float* rowsum = (float*)alloc(NN_ * 4);
    float* cbuf   = (float*)alloc(256);
    float* Pp = (float*)alloc((size_t)4 * NN_ * NN_ * 4);  // split-K partials
    // Tp (2 x 2048x768 f32 = 12.6 MB) aliases the NS-temp region (~14.2 MB);
    // NS temps are dead before first Tp use (RT GEMM). Pp is NOT aliased.
    float* Tp = (float*)(wsb + overlay);
    const size_t TPS = (size_t)BB * NN_;

    (void)hipMemsetAsync(wbuf, 0, (size_t)BB * MM * sizeof(float), stream);

    const dim3 blk(256);
    const dim3 gsk(NN_ / 64, NN_ / 64, 4);
    const int  RED = (NN_ * NN_ / 4) / 256;   // 576

    rownorm_kernel<<<MM, blk, 0, stream>>>(w, wnH, wnL, wnTH, wnTL);

    // adotb = x @ wn^T (M2048 N3072 K768); emit y2_0 = fp16(adotb)
    gemm_big<32,48,1,8,24,0,0,1,0><<<1536, blk, 0, stream>>>(
        x, nullptr, NN_, 0, wnH, wnL, NN_, adotb, MM, 0, NN_,
        nullptr, nullptr, nullptr, y2h, nullptr, nullptr);

    // G = wn^T wn + I (768x768, K=3072), split-K=4 + reduce(+I, split)
    gemm_sk<1><<<gsk, blk, 0, stream>>>(
        nullptr, wnTH, wnTL, MM, wnTH, wnTL, MM, Pp, MM / 4);
    red_ns<1><<<RED, blk, 0, stream>>>(Pp, nullptr, G, GH, GL);

    rowabs_kernel<<<NN_, blk, 0, stream>>>(G, rowsum);
    cmax_kernel<<<1, blk, 0, stream>>>(rowsum, cbuf);
    initdiag_kernel<<<(NN_ * NN_) / 256, blk, 0, stream>>>(X0, cbuf);

    // Newton-Schulz X <- 2X - XGX, 7 iterations, split-K=4 per GEMM
    float* Xc = X0;
    float* Xn = X1;
    for (int it = 0; it < 7; ++it) {
        gemm_sk<0><<<gsk, blk, 0, stream>>>(
            Xc, nullptr, nullptr, NN_, GH, GL, NN_, Pp, NN_ / 4);
        red_ns<0><<<RED, blk, 0, stream>>>(Pp, nullptr, Yb, YbH, YbL);
        gemm_sk<0><<<gsk, blk, 0, stream>>>(
            Xc, nullptr, nullptr, NN_, YbH, YbL, NN_, Pp, NN_ / 4);
        red_ns<2><<<RED, blk, 0, stream>>>(Pp, Xc, Xn, QH, QL);
        float* t = Xc; Xc = Xn; Xn = t;
    }
    // QH/QL = fp16 split of G^{-1}

    // RT = wn @ Ginv (M3072 N768 K768); emit RTH/RTL (f32 copy to Tp scratch)
    gemm_big<48,12,1,12,6,1,0,2,0><<<576, blk, 0, stream>>>(
        nullptr, wnH, NN_, 0, QH, QL, NN_, Tp, NN_, 0, NN_,
        nullptr, nullptr, nullptr, nullptr, RTH, RTL);

    // ADMM loop: T = y2 @ wn (KS=2 partials); w-update consumes partial sum
    for (int it = 0; it < 20; ++it) {
        gemm_big<32,12,2,16,6,1,0,0,0><<<768, blk, 0, stream>>>(
            nullptr, y2h, MM, 0, wnTH, wnTL, MM, Tp, NN_, TPS, MM / 2,
            nullptr, nullptr, nullptr, nullptr, nullptr, nullptr);
        if (it < 19) {
            gemm_big<32,48,1,8,24,3,3,0,0><<<1536, blk, 0, stream>>>(
                Tp, nullptr, NN_, TPS, RTH, RTL, NN_, nullptr, MM, 0, NN_,
                adotb, wbuf, nullptr, y2h, nullptr, nullptr);
        } else {
            gemm_big<32,48,1,8,24,3,3,0,1><<<1536, blk, 0, stream>>>(
                Tp, nullptr, NN_, TPS, RTH, RTL, NN_, nullptr, MM, 0, NN_,
                adotb, wbuf, z, nullptr, nullptr, nullptr);
        }
    }

    // decoded = z @ wn (M2048 N768 K3072), KS=2 partials + reduce
    gemm_big<32,12,2,16,6,0,0,0,0><<<768, blk, 0, stream>>>(
        z, nullptr, MM, 0, wnTH, wnTL, MM, Tp, NN_, TPS, MM / 2,
        nullptr, nullptr, nullptr, nullptr, nullptr, nullptr);
    add2_kernel<<<(BB * NN_ / 4) / 256, blk, 0, stream>>>(Tp, TPS, dec);
}

// Round 11
// 2236.180 us; speedup vs baseline: 1.0500x; 1.0290x over previous
//
#include <hip/hip_runtime.h>
#include <math.h>

#define BB   2048
#define NN_  768
#define MM   3072
#define LAMBD 0.1f

typedef __attribute__((ext_vector_type(8))) _Float16 half8;
typedef __attribute__((ext_vector_type(4))) float  f32x4;
typedef __attribute__((ext_vector_type(4))) unsigned short us4;

union HB { _Float16 f; unsigned short u; };
struct HL { unsigned short h, l; };

__device__ __forceinline__ unsigned short h_bits(float f) {
    HB b; b.f = (_Float16)f; return b.u;
}
__device__ __forceinline__ HL split2h(float f) {
    HL r;
    HB b; b.f = (_Float16)f;
    r.h = b.u;
    const float fh = (float)b.f;
    HB c; c.f = (_Float16)(f - fh);
    r.l = c.u;
    return r;
}
__device__ __forceinline__ float clampl(float x) {
    return fminf(fmaxf(x, -LAMBD), LAMBD);
}

// ---------------------------------------------------------------------------
// Split-K small GEMM (768x768 out, fp16 3-term), 64x64 tile, reg-prefetch,
// single LDS buffer (R8-proven) + transposed (coalesced) epilogue.
// Grid: (12, 12, KS). Writes f32 partials P[ks*768^2 + idx].
// ---------------------------------------------------------------------------
template<int APRE>
__global__ __launch_bounds__(256)
void gemm_sk(const float* __restrict__ A,
             const unsigned short* __restrict__ Ah,
             const unsigned short* __restrict__ Al,
             int lda,
             const unsigned short* __restrict__ Bh,
             const unsigned short* __restrict__ Bl,
             int ldb,
             float* __restrict__ P, int Kper)
{
    __shared__ __align__(16) char smem[20480];
    unsigned short (*AsH)[40] = (unsigned short (*)[40])(smem);
    unsigned short (*AsL)[40] = (unsigned short (*)[40])(smem + 5120);
    unsigned short (*BsH)[40] = (unsigned short (*)[40])(smem + 10240);
    unsigned short (*BsL)[40] = (unsigned short (*)[40])(smem + 15360);

    const int tid  = threadIdx.x;
    const int brow = blockIdx.y * 64;
    const int bcol = blockIdx.x * 64;
    const int koff = blockIdx.z * Kper;
    const int wave = tid >> 6, lane = tid & 63;
    const int wr = wave >> 1, wc = wave & 1;
    const int lrow = lane & 15, kg = lane >> 4;

    const int sk4  = (tid & 7) << 2;

    us4   rAh[2], rAl[2], rBh[2], rBl[2];
    float4 rAf[2];

    auto LOAD = [&](int k0) {
        #pragma unroll
        for (int p = 0; p < 2; ++p) {
            const int row = (p * 256 + tid) >> 3;
            const size_t ga = (size_t)(brow + row) * lda + k0 + sk4;
            const size_t gb = (size_t)(bcol + row) * ldb + k0 + sk4;
            if constexpr (APRE) {
                rAh[p] = *(const us4*)(Ah + ga);
                rAl[p] = *(const us4*)(Al + ga);
            } else {
                rAf[p] = *(const float4*)(A + ga);
            }
            rBh[p] = *(const us4*)(Bh + gb);
            rBl[p] = *(const us4*)(Bl + gb);
        }
    };
    auto STORE = [&]() {
        #pragma unroll
        for (int p = 0; p < 2; ++p) {
            const int row = (p * 256 + tid) >> 3;
            if constexpr (APRE) {
                *(us4*)&AsH[row][sk4] = rAh[p];
                *(us4*)&AsL[row][sk4] = rAl[p];
            } else {
                const HL sx = split2h(rAf[p].x), sy = split2h(rAf[p].y);
                const HL sz = split2h(rAf[p].z), sw = split2h(rAf[p].w);
                us4 h, l;
                h.x = sx.h; l.x = sx.l; h.y = sy.h; l.y = sy.l;
                h.z = sz.h; l.z = sz.l; h.w = sw.h; l.w = sw.l;
                *(us4*)&AsH[row][sk4] = h;
                *(us4*)&AsL[row][sk4] = l;
            }
            *(us4*)&BsH[row][sk4] = rBh[p];
            *(us4*)&BsL[row][sk4] = rBl[p];
        }
    };

    f32x4 acc[2][2];
    #pragma unroll
    for (int m = 0; m < 2; ++m)
        #pragma unroll
        for (int n = 0; n < 2; ++n)
            #pragma unroll
            for (int q = 0; q < 4; ++q) acc[m][n][q] = 0.0f;

    const int NK = Kper / 32;
    LOAD(koff);
    STORE();
    __syncthreads();

    for (int ki = 0; ki < NK; ++ki) {
        if (ki + 1 < NK) LOAD(koff + (ki + 1) * 32);

        half8 ahi[2], alo[2], bhi[2], blo[2];
        #pragma unroll
        for (int m = 0; m < 2; ++m) {
            const int r = wr * 32 + m * 16 + lrow;
            ahi[m] = *(const half8*)&AsH[r][kg * 8];
            alo[m] = *(const half8*)&AsL[r][kg * 8];
        }
        #pragma unroll
        for (int n = 0; n < 2; ++n) {
            const int c = wc * 32 + n * 16 + lrow;
            bhi[n] = *(const half8*)&BsH[c][kg * 8];
            blo[n] = *(const half8*)&BsL[c][kg * 8];
        }
        #pragma unroll
        for (int m = 0; m < 2; ++m)
            #pragma unroll
            for (int n = 0; n < 2; ++n) {
                acc[m][n] = __builtin_amdgcn_mfma_f32_16x16x32_f16(ahi[m], bhi[n], acc[m][n], 0, 0, 0);
                acc[m][n] = __builtin_amdgcn_mfma_f32_16x16x32_f16(ahi[m], blo[n], acc[m][n], 0, 0, 0);
                acc[m][n] = __builtin_amdgcn_mfma_f32_16x16x32_f16(alo[m], bhi[n], acc[m][n], 0, 0, 0);
            }
        __syncthreads();
        if (ki + 1 < NK) { STORE(); __syncthreads(); }
    }

    // transposed epilogue: acc -> LDS [64][65] -> coalesced float4 rows
    float* eb = (float*)smem;
    #pragma unroll
    for (int m = 0; m < 2; ++m)
        #pragma unroll
        for (int n = 0; n < 2; ++n)
            #pragma unroll
            for (int r = 0; r < 4; ++r)
                eb[(wr * 32 + m * 16 + kg * 4 + r) * 65 + wc * 32 + n * 16 + lrow] = acc[m][n][r];
    __syncthreads();
    float* Pk = P + (size_t)blockIdx.z * NN_ * NN_;
    #pragma unroll
    for (int j = 0; j < 4; ++j) {
        const int row = wave * 16 + j * 4 + (lane >> 4);
        const int col = (lane & 15) * 4;
        const float4 v = *(const float4*)&eb[row * 65 + col];
        *(float4*)(Pk + (size_t)(brow + row) * NN_ + bcol + col) = v;
    }
}

// Reduce 4 split-K partials with epilogue. MODE: 0 plain, 1 +I, 2 2*E1-sum.
template<int MODE>
__global__ __launch_bounds__(256)
void red_ns(const float* __restrict__ P,
            const float* __restrict__ E1,
            float* __restrict__ C,
            unsigned short* __restrict__ Ch,
            unsigned short* __restrict__ Cl)
{
    const size_t i4 = ((size_t)blockIdx.x * 256 + threadIdx.x) * 4;
    const size_t sz = (size_t)NN_ * NN_;
    float4 s = *(const float4*)(P + i4);
    const float4 s1 = *(const float4*)(P + sz + i4);
    const float4 s2 = *(const float4*)(P + 2 * sz + i4);
    const float4 s3 = *(const float4*)(P + 3 * sz + i4);
    s.x = (s.x + s1.x) + (s2.x + s3.x);
    s.y = (s.y + s1.y) + (s2.y + s3.y);
    s.z = (s.z + s1.z) + (s2.z + s3.z);
    s.w = (s.w + s1.w) + (s2.w + s3.w);
    float v[4] = {s.x, s.y, s.z, s.w};
    if constexpr (MODE == 1) {
        const int row = (int)(i4 / NN_);
        const int col = (int)(i4 - (size_t)row * NN_);
        #pragma unroll
        for (int j = 0; j < 4; ++j) if (row == col + j) v[j] += 1.0f;
    }
    if constexpr (MODE == 2) {
        const float4 e = *(const float4*)(E1 + i4);
        v[0] = 2.0f * e.x - v[0]; v[1] = 2.0f * e.y - v[1];
        v[2] = 2.0f * e.z - v[2]; v[3] = 2.0f * e.w - v[3];
    }
    float4 o; o.x = v[0]; o.y = v[1]; o.z = v[2]; o.w = v[3];
    *(float4*)(C + i4) = o;
    us4 h, l;
    const HL a = split2h(v[0]), b = split2h(v[1]);
    const HL c = split2h(v[2]), d = split2h(v[3]);
    h.x = a.h; l.x = a.l; h.y = b.h; l.y = b.l;
    h.z = c.h; l.z = c.l; h.w = d.h; l.w = d.l;
    *(us4*)(Ch + i4) = h;
    *(us4*)(Cl + i4) = l;
}

// ---------------------------------------------------------------------------
// Big fp16 2-term GEMM: 64x64 tile, 4 waves (32x32), BK=32, reg-prefetch,
// single LDS buffer (R8-proven main loop) + transposed (coalesced) epilogue.
// A: staged fp16 hi only. B: pre-split fp16 h/l read as [col][k].
// AMODE: 0 = f32 A; 1 = pre-cvt fp16 (Ah); 3 = f32 A + A[psz] partial sum.
// EPI: 0 = C[cks*ks+idx]=acc (+EMIT); 3 = ADMM w-update (y2 emit / LASTZ->z).
// EMIT: 0 none, 1 Y2=fp16(acc), 2 EH/EL = split fp16(acc).
// Grid: flat NBM*NBN*KS; per-XCD 2D patch PM x PN for L2 reuse.
// ---------------------------------------------------------------------------
template<int NBM, int NBN, int KS, int PM, int PN, int AMODE, int EPI, int EMIT, int LASTZ>
__global__ __launch_bounds__(256)
void gemm_big(const float* __restrict__ A,
              const unsigned short* __restrict__ Ah,
              int lda, size_t psz,
              const unsigned short* __restrict__ Bh,
              const unsigned short* __restrict__ Bl,
              int ldb,
              float* __restrict__ C, int ldc, size_t cks, int Kper,
              const float* __restrict__ F1,
              float* __restrict__ Wio,
              float* __restrict__ OutZ,
              unsigned short* __restrict__ Y2,
              unsigned short* __restrict__ EH,
              unsigned short* __restrict__ EL)
{
    static_assert(NBM % PM == 0 && NBN % PN == 0, "patch divides grid");
    constexpr int XM = NBM / PM, XN = NBN / PN;
    static_assert(XM * XN * KS == 8, "patches x KS must equal 8 XCDs");
    static_assert(PM * PN == (NBM * NBN * KS) / 8, "slot count");

    __shared__ __align__(16) char smem[16640];
    unsigned short (*AsH)[40] = (unsigned short (*)[40])(smem);
    unsigned short (*BsH)[40] = (unsigned short (*)[40])(smem + 5120);
    unsigned short (*BsL)[40] = (unsigned short (*)[40])(smem + 10240);

    const int bid  = blockIdx.x;
    const int xcd  = bid & 7;
    const int slot = bid >> 3;
    const int ks   = xcd % KS;
    const int rest = xcd / KS;
    const int xn   = rest % XN;
    const int xm   = rest / XN;
    const int m_   = xm * PM + slot / PN;
    const int n_   = xn * PN + slot % PN;
    const int brow = m_ * 64;
    const int bcol = n_ * 64;
    const int koff = ks * Kper;

    const int tid  = threadIdx.x;
    const int wave = tid >> 6, lane = tid & 63;
    const int wr = wave >> 1, wc = wave & 1;
    const int lrow = lane & 15, kg = lane >> 4;

    const int srow = tid >> 2, sk8 = (tid & 3) << 3;

    uint4  pA0, pB0, pB1;
    float4 pF[2], pG[2];

    auto LOAD = [&](int k0) {
        const size_t ga = (size_t)(brow + srow) * lda + k0 + sk8;
        if constexpr (AMODE == 1) {
            pA0 = *(const uint4*)(Ah + ga);
        } else {
            pF[0] = *(const float4*)(A + ga);
            pF[1] = *(const float4*)(A + ga + 4);
            if constexpr (AMODE == 3) {
                pG[0] = *(const float4*)(A + ga + psz);
                pG[1] = *(const float4*)(A + ga + psz + 4);
            }
        }
        const size_t gb = (size_t)(bcol + srow) * ldb + k0 + sk8;
        pB0 = *(const uint4*)(Bh + gb);
        pB1 = *(const uint4*)(Bl + gb);
    };
    auto STORE = [&]() {
        if constexpr (AMODE == 1) {
            *(uint4*)&AsH[srow][sk8] = pA0;
        } else {
            float va[8];
            va[0] = pF[0].x; va[1] = pF[0].y; va[2] = pF[0].z; va[3] = pF[0].w;
            va[4] = pF[1].x; va[5] = pF[1].y; va[6] = pF[1].z; va[7] = pF[1].w;
            if constexpr (AMODE == 3) {
                va[0] += pG[0].x; va[1] += pG[0].y; va[2] += pG[0].z; va[3] += pG[0].w;
                va[4] += pG[1].x; va[5] += pG[1].y; va[6] += pG[1].z; va[7] += pG[1].w;
            }
            half8 h0;
            #pragma unroll
            for (int j = 0; j < 8; ++j) h0[j] = (_Float16)va[j];
            *(half8*)&AsH[srow][sk8] = h0;
        }
        *(uint4*)&BsH[srow][sk8] = pB0;
        *(uint4*)&BsL[srow][sk8] = pB1;
    };

    f32x4 acc[2][2];
    #pragma unroll
    for (int m = 0; m < 2; ++m)
        #pragma unroll
        for (int n = 0; n < 2; ++n)
            #pragma unroll
            for (int q = 0; q < 4; ++q) acc[m][n][q] = 0.0f;

    const int NK = Kper / 32;
    LOAD(koff);
    STORE();
    __syncthreads();

    for (int ki = 0; ki < NK; ++ki) {
        if (ki + 1 < NK) LOAD(koff + (ki + 1) * 32);

        half8 ah[2], bh[2], bl[2];
        #pragma unroll
        for (int m = 0; m < 2; ++m)
            ah[m] = *(const half8*)&AsH[wr * 32 + m * 16 + lrow][kg * 8];
        #pragma unroll
        for (int n = 0; n < 2; ++n) {
            const int c = wc * 32 + n * 16 + lrow;
            bh[n] = *(const half8*)&BsH[c][kg * 8];
            bl[n] = *(const half8*)&BsL[c][kg * 8];
        }
        #pragma unroll
        for (int m = 0; m < 2; ++m)
            #pragma unroll
            for (int n = 0; n < 2; ++n) {
                acc[m][n] = __builtin_amdgcn_mfma_f32_16x16x32_f16(ah[m], bh[n], acc[m][n], 0, 0, 0);
                acc[m][n] = __builtin_amdgcn_mfma_f32_16x16x32_f16(ah[m], bl[n], acc[m][n], 0, 0, 0);
            }
        __syncthreads();
        if (ki + 1 < NK) { STORE(); __syncthreads(); }
    }

    // ---- transposed epilogue: acc -> LDS [64][65] -> whole-row float4 I/O ----
    float* eb = (float*)smem;
    #pragma unroll
    for (int m = 0; m < 2; ++m)
        #pragma unroll
        for (int n = 0; n < 2; ++n)
            #pragma unroll
            for (int r = 0; r < 4; ++r)
                eb[(wr * 32 + m * 16 + kg * 4 + r) * 65 + wc * 32 + n * 16 + lrow] = acc[m][n][r];
    __syncthreads();

    #pragma unroll
    for (int j = 0; j < 4; ++j) {
        const int row = wave * 16 + j * 4 + (lane >> 4);
        const int col = (lane & 15) * 4;
        const float4 v = *(const float4*)&eb[row * 65 + col];
        const size_t gi = (size_t)(brow + row) * ldc + bcol + col;
        if constexpr (EPI == 0) {
            *(float4*)(C + cks * ks + gi) = v;
            if constexpr (EMIT == 1) {
                us4 h;
                h.x = h_bits(v.x); h.y = h_bits(v.y);
                h.z = h_bits(v.z); h.w = h_bits(v.w);
                *(us4*)(Y2 + gi) = h;
            }
            if constexpr (EMIT == 2) {
                const HL a = split2h(v.x), b = split2h(v.y);
                const HL c2 = split2h(v.z), d = split2h(v.w);
                us4 h, l;
                h.x = a.h; l.x = a.l; h.y = b.h; l.y = b.l;
                h.z = c2.h; l.z = c2.l; h.w = d.h; l.w = d.l;
                *(us4*)(EH + gi) = h;
                *(us4*)(EL + gi) = l;
            }
        } else { // EPI == 3: ADMM w-update, fully coalesced streams
            const float4 f1 = *(const float4*)(F1 + gi);
            const float4 ww = *(const float4*)(Wio + gi);
            float wn0 = f1.x + ww.x - clampl(ww.x) - v.x;
            float wn1 = f1.y + ww.y - clampl(ww.y) - v.y;
            float wn2 = f1.z + ww.z - clampl(ww.z) - v.z;
            float wn3 = f1.w + ww.w - clampl(ww.w) - v.w;
            if constexpr (LASTZ) {
                float4 o;
                o.x = wn0 - clampl(wn0); o.y = wn1 - clampl(wn1);
                o.z = wn2 - clampl(wn2); o.w = wn3 - clampl(wn3);
                *(float4*)(OutZ + gi) = o;
            } else {
                float4 o; o.x = wn0; o.y = wn1; o.z = wn2; o.w = wn3;
                *(float4*)(Wio + gi) = o;
                us4 h;
                h.x = h_bits(f1.x + wn0 - 2.0f * clampl(wn0));
                h.y = h_bits(f1.y + wn1 - 2.0f * clampl(wn1));
                h.z = h_bits(f1.z + wn2 - 2.0f * clampl(wn2));
                h.w = h_bits(f1.w + wn3 - 2.0f * clampl(wn3));
                *(us4*)(Y2 + gi) = h;
            }
        }
    }
}

// Normalize rows of weight (3072x768); emit fp16 h/l of wn and wn^T.
__global__ __launch_bounds__(256)
void rownorm_kernel(const float* __restrict__ W,
                    unsigned short* __restrict__ wnH, unsigned short* __restrict__ wnL,
                    unsigned short* __restrict__ wnTH, unsigned short* __restrict__ wnTL)
{
    __shared__ float red[256];
    const int row = blockIdx.x;
    const int t = threadIdx.x;
    const float* wr = W + (size_t)row * NN_;
    float s = 0.0f;
    for (int k = t; k < NN_; k += 256) { const float w = wr[k]; s += w * w; }
    red[t] = s; __syncthreads();
    for (int off = 128; off > 0; off >>= 1) {
        if (t < off) red[t] += red[t + off];
        __syncthreads();
    }
    const float rn = 1.0f / sqrtf(red[0]);
    for (int k = t; k < NN_; k += 256) {
        const float v = wr[k] * rn;
        const HL s2 = split2h(v);
        wnH[(size_t)row * NN_ + k] = s2.h;
        wnL[(size_t)row * NN_ + k] = s2.l;
        wnTH[(size_t)k * MM + row] = s2.h;
        wnTL[(size_t)k * MM + row] = s2.l;
    }
}

__global__ __launch_bounds__(256)
void rowabs_kernel(const float* __restrict__ G, float* __restrict__ rowsum)
{
    __shared__ float red[256];
    const int row = blockIdx.x;
    const int t = threadIdx.x;
    const float* gr = G + (size_t)row * NN_;
    float s = 0.0f;
    for (int k = t; k < NN_; k += 256) s += fabsf(gr[k]);
    red[t] = s; __syncthreads();
    for (int off = 128; off > 0; off >>= 1) {
        if (t < off) red[t] += red[t + off];
        __syncthreads();
    }
    if (t == 0) rowsum[row] = red[0];
}

__global__ __launch_bounds__(256)
void cmax_kernel(const float* __restrict__ rowsum, float* __restrict__ cbuf)
{
    __shared__ float red[256];
    const int t = threadIdx.x;
    float mx = 0.0f;
    for (int k = t; k < NN_; k += 256) mx = fmaxf(mx, rowsum[k]);
    red[t] = mx; __syncthreads();
    for (int off = 128; off > 0; off >>= 1) {
        if (t < off) red[t] = fmaxf(red[t], red[t + off]);
        __syncthreads();
    }
    if (t == 0) cbuf[0] = 2.0f / (1.0f + red[0]);
}

__global__ __launch_bounds__(256)
void initdiag_kernel(float* __restrict__ X, const float* __restrict__ c)
{
    const int idx = blockIdx.x * 256 + threadIdx.x;
    const int p = idx / NN_, q = idx - p * NN_;
    X[idx] = (p == q) ? c[0] : 0.0f;
}

// dec = p0 + p1 (float4)
__global__ __launch_bounds__(256)
void add2_kernel(const float* __restrict__ p0, size_t ps, float* __restrict__ o)
{
    const size_t i = ((size_t)blockIdx.x * 256 + threadIdx.x) * 4;
    const float4 a = *(const float4*)(p0 + i);
    const float4 b = *(const float4*)(p0 + ps + i);
    float4 v;
    v.x = a.x + b.x; v.y = a.y + b.y;
    v.z = a.z + b.z; v.w = a.w + b.w;
    *(float4*)(o + i) = v;
}

extern "C" void kernel_launch(void* const* d_in, const int* in_sizes, int n_in,
                              void* d_out, int out_size, void* d_ws, size_t ws_size,
                              hipStream_t stream)
{
    const float* x = (const float*)d_in[0];   // (2048, 768)
    const float* w = (const float*)d_in[1];   // (3072, 768)

    float* out = (float*)d_out;
    float* z   = out;                          // (2048, 3072)
    float* dec = out + (size_t)BB * MM;        // (2048, 768)

    char* wsb = (char*)d_ws;
    size_t off = 0;
    auto alloc = [&](size_t bytes) -> void* {
        void* p = wsb + off;
        off += (bytes + 255) & ~(size_t)255;
        return p;
    };
    // --- persistent ---
    unsigned short* wnH  = (unsigned short*)alloc((size_t)MM * NN_ * 2);
    unsigned short* wnL  = (unsigned short*)alloc((size_t)MM * NN_ * 2);
    unsigned short* wnTH = (unsigned short*)alloc((size_t)MM * NN_ * 2);
    unsigned short* wnTL = (unsigned short*)alloc((size_t)MM * NN_ * 2);
    float* adotb = (float*)alloc((size_t)BB * MM * 4);
    float* wbuf  = (float*)alloc((size_t)BB * MM * 4);
    unsigned short* y2h = (unsigned short*)alloc((size_t)BB * MM * 2);
    unsigned short* QH  = (unsigned short*)alloc((size_t)NN_ * NN_ * 2);
    unsigned short* QL  = (unsigned short*)alloc((size_t)NN_ * NN_ * 2);
    unsigned short* RTH = (unsigned short*)alloc((size_t)MM * NN_ * 2);
    unsigned short* RTL = (unsigned short*)alloc((size_t)MM * NN_ * 2);
    // --- overlay: NS temps (dead after RT) aliased with T/dec partials ---
    const size_t overlay = off;
    float* G  = (float*)alloc((size_t)NN_ * NN_ * 4);
    unsigned short* GH  = (unsigned short*)alloc((size_t)NN_ * NN_ * 2);
    unsigned short* GL  = (unsigned short*)alloc((size_t)NN_ * NN_ * 2);
    float* X0 = (float*)alloc((size_t)NN_ * NN_ * 4);
    float* X1 = (float*)alloc((size_t)NN_ * NN_ * 4);
    float* Yb = (float*)alloc((size_t)NN_ * NN_ * 4);
    unsigned short* YbH = (unsigned short*)alloc((size_t)NN_ * NN_ * 2);
    unsigned short* YbL = (unsigned short*)alloc((size_t)NN_ * NN_ * 2);
    float* rowsum = (float*)alloc(NN_ * 4);
    float* cbuf   = (float*)alloc(256);
    float* Pp = (float*)alloc((size_t)4 * NN_ * NN_ * 4);  // split-K partials
    // Tp (2 x 2048x768 f32 = 12.6 MB) aliases the NS-temp region (~14.2 MB);
    // NS temps are dead before first Tp use (RT GEMM). Pp is NOT aliased.
    float* Tp = (float*)(wsb + overlay);
    const size_t TPS = (size_t)BB * NN_;

    (void)hipMemsetAsync(wbuf, 0, (size_t)BB * MM * sizeof(float), stream);

    const dim3 blk(256);
    const dim3 gsk(NN_ / 64, NN_ / 64, 4);
    const int  RED = (NN_ * NN_ / 4) / 256;   // 576

    rownorm_kernel<<<MM, blk, 0, stream>>>(w, wnH, wnL, wnTH, wnTL);

    // adotb = x @ wn^T (M2048 N3072 K768); emit y2_0 = fp16(adotb)
    gemm_big<32,48,1,8,24,0,0,1,0><<<1536, blk, 0, stream>>>(
        x, nullptr, NN_, 0, wnH, wnL, NN_, adotb, MM, 0, NN_,
        nullptr, nullptr, nullptr, y2h, nullptr, nullptr);

    // G = wn^T wn + I (768x768, K=3072), split-K=4 + reduce(+I, split)
    gemm_sk<1><<<gsk, blk, 0, stream>>>(
        nullptr, wnTH, wnTL, MM, wnTH, wnTL, MM, Pp, MM / 4);
    red_ns<1><<<RED, blk, 0, stream>>>(Pp, nullptr, G, GH, GL);

    rowabs_kernel<<<NN_, blk, 0, stream>>>(G, rowsum);
    cmax_kernel<<<1, blk, 0, stream>>>(rowsum, cbuf);
    initdiag_kernel<<<(NN_ * NN_) / 256, blk, 0, stream>>>(X0, cbuf);

    // Newton-Schulz X <- 2X - XGX, 7 iterations, split-K=4 per GEMM
    float* Xc = X0;
    float* Xn = X1;
    for (int it = 0; it < 7; ++it) {
        gemm_sk<0><<<gsk, blk, 0, stream>>>(
            Xc, nullptr, nullptr, NN_, GH, GL, NN_, Pp, NN_ / 4);
        red_ns<0><<<RED, blk, 0, stream>>>(Pp, nullptr, Yb, YbH, YbL);
        gemm_sk<0><<<gsk, blk, 0, stream>>>(
            Xc, nullptr, nullptr, NN_, YbH, YbL, NN_, Pp, NN_ / 4);
        red_ns<2><<<RED, blk, 0, stream>>>(Pp, Xc, Xn, QH, QL);
        float* t = Xc; Xc = Xn; Xn = t;
    }
    // QH/QL = fp16 split of G^{-1}

    // RT = wn @ Ginv (M3072 N768 K768); emit RTH/RTL (f32 copy to Tp scratch)
    gemm_big<48,12,1,12,6,1,0,2,0><<<576, blk, 0, stream>>>(
        nullptr, wnH, NN_, 0, QH, QL, NN_, Tp, NN_, 0, NN_,
        nullptr, nullptr, nullptr, nullptr, RTH, RTL);

    // ADMM loop: T = y2 @ wn (KS=2 partials); w-update consumes partial sum
    for (int it = 0; it < 20; ++it) {
        gemm_big<32,12,2,16,6,1,0,0,0><<<768, blk, 0, stream>>>(
            nullptr, y2h, MM, 0, wnTH, wnTL, MM, Tp, NN_, TPS, MM / 2,
            nullptr, nullptr, nullptr, nullptr, nullptr, nullptr);
        if (it < 19) {
            gemm_big<32,48,1,8,24,3,3,0,0><<<1536, blk, 0, stream>>>(
                Tp, nullptr, NN_, TPS, RTH, RTL, NN_, nullptr, MM, 0, NN_,
                adotb, wbuf, nullptr, y2h, nullptr, nullptr);
        } else {
            gemm_big<32,48,1,8,24,3,3,0,1><<<1536, blk, 0, stream>>>(
                Tp, nullptr, NN_, TPS, RTH, RTL, NN_, nullptr, MM, 0, NN_,
                adotb, wbuf, z, nullptr, nullptr, nullptr);
        }
    }

    // decoded = z @ wn (M2048 N768 K3072), KS=2 partials + reduce
    gemm_big<32,12,2,16,6,0,0,0,0><<<768, blk, 0, stream>>>(
        z, nullptr, MM, 0, wnTH, wnTL, MM, Tp, NN_, TPS, MM / 2,
        nullptr, nullptr, nullptr, nullptr, nullptr, nullptr);
    add2_kernel<<<(BB * NN_ / 4) / 256, blk, 0, stream>>>(Tp, TPS, dec);
}

// Round 12
// 2148.444 us; speedup vs baseline: 1.0929x; 1.0408x over previous
//
#include <hip/hip_runtime.h>
#include <math.h>

#define BB   2048
#define NN_  768
#define MM   3072
#define LAMBD 0.1f

typedef __attribute__((ext_vector_type(8))) _Float16 half8;
typedef __attribute__((ext_vector_type(4))) float  f32x4;
typedef __attribute__((ext_vector_type(4))) unsigned short us4;

union HB { _Float16 f; unsigned short u; };
struct HL { unsigned short h, l; };

__device__ __forceinline__ unsigned short h_bits(float f) {
    HB b; b.f = (_Float16)f; return b.u;
}
__device__ __forceinline__ HL split2h(float f) {
    HL r;
    HB b; b.f = (_Float16)f;
    r.h = b.u;
    const float fh = (float)b.f;
    HB c; c.f = (_Float16)(f - fh);
    r.l = c.u;
    return r;
}
__device__ __forceinline__ float clampl(float x) {
    return fminf(fmaxf(x, -LAMBD), LAMBD);
}

// ---------------------------------------------------------------------------
// Split-K small GEMM (768x768 out, fp16 3-term), 64x64 tile, reg-prefetch,
// single LDS buffer + transposed (coalesced) epilogue. Grid: (12, 12, KS).
// ---------------------------------------------------------------------------
template<int APRE>
__global__ __launch_bounds__(256)
void gemm_sk(const float* __restrict__ A,
             const unsigned short* __restrict__ Ah,
             const unsigned short* __restrict__ Al,
             int lda,
             const unsigned short* __restrict__ Bh,
             const unsigned short* __restrict__ Bl,
             int ldb,
             float* __restrict__ P, int Kper)
{
    __shared__ __align__(16) char smem[20480];
    unsigned short (*AsH)[40] = (unsigned short (*)[40])(smem);
    unsigned short (*AsL)[40] = (unsigned short (*)[40])(smem + 5120);
    unsigned short (*BsH)[40] = (unsigned short (*)[40])(smem + 10240);
    unsigned short (*BsL)[40] = (unsigned short (*)[40])(smem + 15360);

    const int tid  = threadIdx.x;
    const int brow = blockIdx.y * 64;
    const int bcol = blockIdx.x * 64;
    const int koff = blockIdx.z * Kper;
    const int wave = tid >> 6, lane = tid & 63;
    const int wr = wave >> 1, wc = wave & 1;
    const int lrow = lane & 15, kg = lane >> 4;

    const int sk4  = (tid & 7) << 2;

    us4   rAh[2], rAl[2], rBh[2], rBl[2];
    float4 rAf[2];

    auto LOAD = [&](int k0) {
        #pragma unroll
        for (int p = 0; p < 2; ++p) {
            const int row = (p * 256 + tid) >> 3;
            const size_t ga = (size_t)(brow + row) * lda + k0 + sk4;
            const size_t gb = (size_t)(bcol + row) * ldb + k0 + sk4;
            if constexpr (APRE) {
                rAh[p] = *(const us4*)(Ah + ga);
                rAl[p] = *(const us4*)(Al + ga);
            } else {
                rAf[p] = *(const float4*)(A + ga);
            }
            rBh[p] = *(const us4*)(Bh + gb);
            rBl[p] = *(const us4*)(Bl + gb);
        }
    };
    auto STORE = [&]() {
        #pragma unroll
        for (int p = 0; p < 2; ++p) {
            const int row = (p * 256 + tid) >> 3;
            if constexpr (APRE) {
                *(us4*)&AsH[row][sk4] = rAh[p];
                *(us4*)&AsL[row][sk4] = rAl[p];
            } else {
                const HL sx = split2h(rAf[p].x), sy = split2h(rAf[p].y);
                const HL sz = split2h(rAf[p].z), sw = split2h(rAf[p].w);
                us4 h, l;
                h.x = sx.h; l.x = sx.l; h.y = sy.h; l.y = sy.l;
                h.z = sz.h; l.z = sz.l; h.w = sw.h; l.w = sw.l;
                *(us4*)&AsH[row][sk4] = h;
                *(us4*)&AsL[row][sk4] = l;
            }
            *(us4*)&BsH[row][sk4] = rBh[p];
            *(us4*)&BsL[row][sk4] = rBl[p];
        }
    };

    f32x4 acc[2][2];
    #pragma unroll
    for (int m = 0; m < 2; ++m)
        #pragma unroll
        for (int n = 0; n < 2; ++n)
            #pragma unroll
            for (int q = 0; q < 4; ++q) acc[m][n][q] = 0.0f;

    const int NK = Kper / 32;
    LOAD(koff);
    STORE();
    __syncthreads();

    for (int ki = 0; ki < NK; ++ki) {
        if (ki + 1 < NK) LOAD(koff + (ki + 1) * 32);

        half8 ahi[2], alo[2], bhi[2], blo[2];
        #pragma unroll
        for (int m = 0; m < 2; ++m) {
            const int r = wr * 32 + m * 16 + lrow;
            ahi[m] = *(const half8*)&AsH[r][kg * 8];
            alo[m] = *(const half8*)&AsL[r][kg * 8];
        }
        #pragma unroll
        for (int n = 0; n < 2; ++n) {
            const int c = wc * 32 + n * 16 + lrow;
            bhi[n] = *(const half8*)&BsH[c][kg * 8];
            blo[n] = *(const half8*)&BsL[c][kg * 8];
        }
        #pragma unroll
        for (int m = 0; m < 2; ++m)
            #pragma unroll
            for (int n = 0; n < 2; ++n) {
                acc[m][n] = __builtin_amdgcn_mfma_f32_16x16x32_f16(ahi[m], bhi[n], acc[m][n], 0, 0, 0);
                acc[m][n] = __builtin_amdgcn_mfma_f32_16x16x32_f16(ahi[m], blo[n], acc[m][n], 0, 0, 0);
                acc[m][n] = __builtin_amdgcn_mfma_f32_16x16x32_f16(alo[m], bhi[n], acc[m][n], 0, 0, 0);
            }
        __syncthreads();
        if (ki + 1 < NK) { STORE(); __syncthreads(); }
    }

    // transposed epilogue: acc -> LDS [64][65] -> coalesced float4 rows
    float* eb = (float*)smem;
    #pragma unroll
    for (int m = 0; m < 2; ++m)
        #pragma unroll
        for (int n = 0; n < 2; ++n)
            #pragma unroll
            for (int r = 0; r < 4; ++r)
                eb[(wr * 32 + m * 16 + kg * 4 + r) * 65 + wc * 32 + n * 16 + lrow] = acc[m][n][r];
    __syncthreads();
    float* Pk = P + (size_t)blockIdx.z * NN_ * NN_;
    #pragma unroll
    for (int j = 0; j < 4; ++j) {
        const int row = wave * 16 + j * 4 + (lane >> 4);
        const int col = (lane & 15) * 4;
        const float4 v = *(const float4*)&eb[row * 65 + col];
        *(float4*)(Pk + (size_t)(brow + row) * NN_ + bcol + col) = v;
    }
}

// Reduce 4 split-K partials with epilogue. MODE: 0 plain, 1 +I, 2 2*E1-sum.
template<int MODE>
__global__ __launch_bounds__(256)
void red_ns(const float* __restrict__ P,
            const float* __restrict__ E1,
            float* __restrict__ C,
            unsigned short* __restrict__ Ch,
            unsigned short* __restrict__ Cl)
{
    const size_t i4 = ((size_t)blockIdx.x * 256 + threadIdx.x) * 4;
    const size_t sz = (size_t)NN_ * NN_;
    float4 s = *(const float4*)(P + i4);
    const float4 s1 = *(const float4*)(P + sz + i4);
    const float4 s2 = *(const float4*)(P + 2 * sz + i4);
    const float4 s3 = *(const float4*)(P + 3 * sz + i4);
    s.x = (s.x + s1.x) + (s2.x + s3.x);
    s.y = (s.y + s1.y) + (s2.y + s3.y);
    s.z = (s.z + s1.z) + (s2.z + s3.z);
    s.w = (s.w + s1.w) + (s2.w + s3.w);
    float v[4] = {s.x, s.y, s.z, s.w};
    if constexpr (MODE == 1) {
        const int row = (int)(i4 / NN_);
        const int col = (int)(i4 - (size_t)row * NN_);
        #pragma unroll
        for (int j = 0; j < 4; ++j) if (row == col + j) v[j] += 1.0f;
    }
    if constexpr (MODE == 2) {
        const float4 e = *(const float4*)(E1 + i4);
        v[0] = 2.0f * e.x - v[0]; v[1] = 2.0f * e.y - v[1];
        v[2] = 2.0f * e.z - v[2]; v[3] = 2.0f * e.w - v[3];
    }
    float4 o; o.x = v[0]; o.y = v[1]; o.z = v[2]; o.w = v[3];
    *(float4*)(C + i4) = o;
    us4 h, l;
    const HL a = split2h(v[0]), b = split2h(v[1]);
    const HL c = split2h(v[2]), d = split2h(v[3]);
    h.x = a.h; l.x = a.l; h.y = b.h; l.y = b.l;
    h.z = c.h; l.z = c.l; h.w = d.h; l.w = d.l;
    *(us4*)(Ch + i4) = h;
    *(us4*)(Cl + i4) = l;
}

// ---------------------------------------------------------------------------
// Big fp16 2-term GEMM: 64x64 tile, 4 waves (32x32), BK=32, reg-prefetch,
// single LDS buffer + transposed (coalesced) epilogue.
// AMODE: 0 f32 A; 1 pre-cvt fp16 (Ah); 3 f32 A + A[psz] sum;
//        4 fp16 Ah + Ah[psz] pair, summed in half8 (T partials).
// EPI: 0 C=acc f32 (+EMIT); 3 ADMM w-update; 4 fp16 partial -> Y2[cks*ks+gi].
// EMIT: 0 none, 1 Y2=fp16(acc), 2 EH/EL = split fp16(acc).
// Grid: flat NBM*NBN*KS; per-XCD 2D patch PM x PN for L2 reuse.
// ---------------------------------------------------------------------------
template<int NBM, int NBN, int KS, int PM, int PN, int AMODE, int EPI, int EMIT, int LASTZ>
__global__ __launch_bounds__(256)
void gemm_big(const float* __restrict__ A,
              const unsigned short* __restrict__ Ah,
              int lda, size_t psz,
              const unsigned short* __restrict__ Bh,
              const unsigned short* __restrict__ Bl,
              int ldb,
              float* __restrict__ C, int ldc, size_t cks, int Kper,
              const float* __restrict__ F1,
              float* __restrict__ Wio,
              float* __restrict__ OutZ,
              unsigned short* __restrict__ Y2,
              unsigned short* __restrict__ EH,
              unsigned short* __restrict__ EL)
{
    static_assert(NBM % PM == 0 && NBN % PN == 0, "patch divides grid");
    constexpr int XM = NBM / PM, XN = NBN / PN;
    static_assert(XM * XN * KS == 8, "patches x KS must equal 8 XCDs");
    static_assert(PM * PN == (NBM * NBN * KS) / 8, "slot count");

    __shared__ __align__(16) char smem[16640];
    unsigned short (*AsH)[40] = (unsigned short (*)[40])(smem);
    unsigned short (*BsH)[40] = (unsigned short (*)[40])(smem + 5120);
    unsigned short (*BsL)[40] = (unsigned short (*)[40])(smem + 10240);

    const int bid  = blockIdx.x;
    const int xcd  = bid & 7;
    const int slot = bid >> 3;
    const int ks   = xcd % KS;
    const int rest = xcd / KS;
    const int xn   = rest % XN;
    const int xm   = rest / XN;
    const int m_   = xm * PM + slot / PN;
    const int n_   = xn * PN + slot % PN;
    const int brow = m_ * 64;
    const int bcol = n_ * 64;
    const int koff = ks * Kper;

    const int tid  = threadIdx.x;
    const int wave = tid >> 6, lane = tid & 63;
    const int wr = wave >> 1, wc = wave & 1;
    const int lrow = lane & 15, kg = lane >> 4;

    const int srow = tid >> 2, sk8 = (tid & 3) << 3;

    uint4  pA0, pA1, pB0, pB1;
    float4 pF[2], pG[2];

    auto LOAD = [&](int k0) {
        const size_t ga = (size_t)(brow + srow) * lda + k0 + sk8;
        if constexpr (AMODE == 1) {
            pA0 = *(const uint4*)(Ah + ga);
        } else if constexpr (AMODE == 4) {
            pA0 = *(const uint4*)(Ah + ga);
            pA1 = *(const uint4*)(Ah + ga + psz);
        } else {
            pF[0] = *(const float4*)(A + ga);
            pF[1] = *(const float4*)(A + ga + 4);
            if constexpr (AMODE == 3) {
                pG[0] = *(const float4*)(A + ga + psz);
                pG[1] = *(const float4*)(A + ga + psz + 4);
            }
        }
        const size_t gb = (size_t)(bcol + srow) * ldb + k0 + sk8;
        pB0 = *(const uint4*)(Bh + gb);
        pB1 = *(const uint4*)(Bl + gb);
    };
    auto STORE = [&]() {
        if constexpr (AMODE == 1) {
            *(uint4*)&AsH[srow][sk8] = pA0;
        } else if constexpr (AMODE == 4) {
            half8 h0 = *(half8*)&pA0;
            half8 h1 = *(half8*)&pA1;
            half8 hs = h0 + h1;
            *(half8*)&AsH[srow][sk8] = hs;
        } else {
            float va[8];
            va[0] = pF[0].x; va[1] = pF[0].y; va[2] = pF[0].z; va[3] = pF[0].w;
            va[4] = pF[1].x; va[5] = pF[1].y; va[6] = pF[1].z; va[7] = pF[1].w;
            if constexpr (AMODE == 3) {
                va[0] += pG[0].x; va[1] += pG[0].y; va[2] += pG[0].z; va[3] += pG[0].w;
                va[4] += pG[1].x; va[5] += pG[1].y; va[6] += pG[1].z; va[7] += pG[1].w;
            }
            half8 h0;
            #pragma unroll
            for (int j = 0; j < 8; ++j) h0[j] = (_Float16)va[j];
            *(half8*)&AsH[srow][sk8] = h0;
        }
        *(uint4*)&BsH[srow][sk8] = pB0;
        *(uint4*)&BsL[srow][sk8] = pB1;
    };

    f32x4 acc[2][2];
    #pragma unroll
    for (int m = 0; m < 2; ++m)
        #pragma unroll
        for (int n = 0; n < 2; ++n)
            #pragma unroll
            for (int q = 0; q < 4; ++q) acc[m][n][q] = 0.0f;

    const int NK = Kper / 32;
    LOAD(koff);
    STORE();
    __syncthreads();

    for (int ki = 0; ki < NK; ++ki) {
        if (ki + 1 < NK) LOAD(koff + (ki + 1) * 32);

        half8 ah[2], bh[2], bl[2];
        #pragma unroll
        for (int m = 0; m < 2; ++m)
            ah[m] = *(const half8*)&AsH[wr * 32 + m * 16 + lrow][kg * 8];
        #pragma unroll
        for (int n = 0; n < 2; ++n) {
            const int c = wc * 32 + n * 16 + lrow;
            bh[n] = *(const half8*)&BsH[c][kg * 8];
            bl[n] = *(const half8*)&BsL[c][kg * 8];
        }
        #pragma unroll
        for (int m = 0; m < 2; ++m)
            #pragma unroll
            for (int n = 0; n < 2; ++n) {
                acc[m][n] = __builtin_amdgcn_mfma_f32_16x16x32_f16(ah[m], bh[n], acc[m][n], 0, 0, 0);
                acc[m][n] = __builtin_amdgcn_mfma_f32_16x16x32_f16(ah[m], bl[n], acc[m][n], 0, 0, 0);
            }
        __syncthreads();
        if (ki + 1 < NK) { STORE(); __syncthreads(); }
    }

    // ---- transposed epilogue: acc -> LDS [64][65] -> whole-row float4 I/O ----
    float* eb = (float*)smem;
    #pragma unroll
    for (int m = 0; m < 2; ++m)
        #pragma unroll
        for (int n = 0; n < 2; ++n)
            #pragma unroll
            for (int r = 0; r < 4; ++r)
                eb[(wr * 32 + m * 16 + kg * 4 + r) * 65 + wc * 32 + n * 16 + lrow] = acc[m][n][r];
    __syncthreads();

    #pragma unroll
    for (int j = 0; j < 4; ++j) {
        const int row = wave * 16 + j * 4 + (lane >> 4);
        const int col = (lane & 15) * 4;
        const float4 v = *(const float4*)&eb[row * 65 + col];
        const size_t gi = (size_t)(brow + row) * ldc + bcol + col;
        if constexpr (EPI == 0) {
            *(float4*)(C + cks * ks + gi) = v;
            if constexpr (EMIT == 1) {
                us4 h;
                h.x = h_bits(v.x); h.y = h_bits(v.y);
                h.z = h_bits(v.z); h.w = h_bits(v.w);
                *(us4*)(Y2 + gi) = h;
            }
            if constexpr (EMIT == 2) {
                const HL a = split2h(v.x), b = split2h(v.y);
                const HL c2 = split2h(v.z), d = split2h(v.w);
                us4 h, l;
                h.x = a.h; l.x = a.l; h.y = b.h; l.y = b.l;
                h.z = c2.h; l.z = c2.l; h.w = d.h; l.w = d.l;
                *(us4*)(EH + gi) = h;
                *(us4*)(EL + gi) = l;
            }
        } else if constexpr (EPI == 4) {   // fp16 partial write (T-GEMM)
            us4 h;
            h.x = h_bits(v.x); h.y = h_bits(v.y);
            h.z = h_bits(v.z); h.w = h_bits(v.w);
            *(us4*)(Y2 + cks * ks + gi) = h;
        } else { // EPI == 3: ADMM w-update, fully coalesced streams
            const float4 f1 = *(const float4*)(F1 + gi);
            const float4 ww = *(const float4*)(Wio + gi);
            float wn0 = f1.x + ww.x - clampl(ww.x) - v.x;
            float wn1 = f1.y + ww.y - clampl(ww.y) - v.y;
            float wn2 = f1.z + ww.z - clampl(ww.z) - v.z;
            float wn3 = f1.w + ww.w - clampl(ww.w) - v.w;
            if constexpr (LASTZ) {
                float4 o;
                o.x = wn0 - clampl(wn0); o.y = wn1 - clampl(wn1);
                o.z = wn2 - clampl(wn2); o.w = wn3 - clampl(wn3);
                *(float4*)(OutZ + gi) = o;
            } else {
                float4 o; o.x = wn0; o.y = wn1; o.z = wn2; o.w = wn3;
                *(float4*)(Wio + gi) = o;
                us4 h;
                h.x = h_bits(f1.x + wn0 - 2.0f * clampl(wn0));
                h.y = h_bits(f1.y + wn1 - 2.0f * clampl(wn1));
                h.z = h_bits(f1.z + wn2 - 2.0f * clampl(wn2));
                h.w = h_bits(f1.w + wn3 - 2.0f * clampl(wn3));
                *(us4*)(Y2 + gi) = h;
            }
        }
    }
}

// Normalize rows of weight (3072x768); emit fp16 h/l of wn and wn^T.
__global__ __launch_bounds__(256)
void rownorm_kernel(const float* __restrict__ W,
                    unsigned short* __restrict__ wnH, unsigned short* __restrict__ wnL,
                    unsigned short* __restrict__ wnTH, unsigned short* __restrict__ wnTL)
{
    __shared__ float red[256];
    const int row = blockIdx.x;
    const int t = threadIdx.x;
    const float* wr = W + (size_t)row * NN_;
    float s = 0.0f;
    for (int k = t; k < NN_; k += 256) { const float w = wr[k]; s += w * w; }
    red[t] = s; __syncthreads();
    for (int off = 128; off > 0; off >>= 1) {
        if (t < off) red[t] += red[t + off];
        __syncthreads();
    }
    const float rn = 1.0f / sqrtf(red[0]);
    for (int k = t; k < NN_; k += 256) {
        const float v = wr[k] * rn;
        const HL s2 = split2h(v);
        wnH[(size_t)row * NN_ + k] = s2.h;
        wnL[(size_t)row * NN_ + k] = s2.l;
        wnTH[(size_t)k * MM + row] = s2.h;
        wnTL[(size_t)k * MM + row] = s2.l;
    }
}

__global__ __launch_bounds__(256)
void rowabs_kernel(const float* __restrict__ G, float* __restrict__ rowsum)
{
    __shared__ float red[256];
    const int row = blockIdx.x;
    const int t = threadIdx.x;
    const float* gr = G + (size_t)row * NN_;
    float s = 0.0f;
    for (int k = t; k < NN_; k += 256) s += fabsf(gr[k]);
    red[t] = s; __syncthreads();
    for (int off = 128; off > 0; off >>= 1) {
        if (t < off) red[t] += red[t + off];
        __syncthreads();
    }
    if (t == 0) rowsum[row] = red[0];
}

__global__ __launch_bounds__(256)
void cmax_kernel(const float* __restrict__ rowsum, float* __restrict__ cbuf)
{
    __shared__ float red[256];
    const int t = threadIdx.x;
    float mx = 0.0f;
    for (int k = t; k < NN_; k += 256) mx = fmaxf(mx, rowsum[k]);
    red[t] = mx; __syncthreads();
    for (int off = 128; off > 0; off >>= 1) {
        if (t < off) red[t] = fmaxf(red[t], red[t + off]);
        __syncthreads();
    }
    if (t == 0) cbuf[0] = 2.0f / (1.0f + red[0]);
}

__global__ __launch_bounds__(256)
void initdiag_kernel(float* __restrict__ X, const float* __restrict__ c)
{
    const int idx = blockIdx.x * 256 + threadIdx.x;
    const int p = idx / NN_, q = idx - p * NN_;
    X[idx] = (p == q) ? c[0] : 0.0f;
}

// dec = p0 + p1 (float4)
__global__ __launch_bounds__(256)
void add2_kernel(const float* __restrict__ p0, size_t ps, float* __restrict__ o)
{
    const size_t i = ((size_t)blockIdx.x * 256 + threadIdx.x) * 4;
    const float4 a = *(const float4*)(p0 + i);
    const float4 b = *(const float4*)(p0 + ps + i);
    float4 v;
    v.x = a.x + b.x; v.y = a.y + b.y;
    v.z = a.z + b.z; v.w = a.w + b.w;
    *(float4*)(o + i) = v;
}

extern "C" void kernel_launch(void* const* d_in, const int* in_sizes, int n_in,
                              void* d_out, int out_size, void* d_ws, size_t ws_size,
                              hipStream_t stream)
{
    const float* x = (const float*)d_in[0];   // (2048, 768)
    const float* w = (const float*)d_in[1];   // (3072, 768)

    float* out = (float*)d_out;
    float* z   = out;                          // (2048, 3072)
    float* dec = out + (size_t)BB * MM;        // (2048, 768)

    char* wsb = (char*)d_ws;
    size_t off = 0;
    auto alloc = [&](size_t bytes) -> void* {
        void* p = wsb + off;
        off += (bytes + 255) & ~(size_t)255;
        return p;
    };
    // --- persistent ---
    unsigned short* wnH  = (unsigned short*)alloc((size_t)MM * NN_ * 2);
    unsigned short* wnL  = (unsigned short*)alloc((size_t)MM * NN_ * 2);
    unsigned short* wnTH = (unsigned short*)alloc((size_t)MM * NN_ * 2);
    unsigned short* wnTL = (unsigned short*)alloc((size_t)MM * NN_ * 2);
    float* adotb = (float*)alloc((size_t)BB * MM * 4);
    float* wbuf  = (float*)alloc((size_t)BB * MM * 4);
    unsigned short* y2h = (unsigned short*)alloc((size_t)BB * MM * 2);
    unsigned short* QH  = (unsigned short*)alloc((size_t)NN_ * NN_ * 2);
    unsigned short* QL  = (unsigned short*)alloc((size_t)NN_ * NN_ * 2);
    unsigned short* RTH = (unsigned short*)alloc((size_t)MM * NN_ * 2);
    unsigned short* RTL = (unsigned short*)alloc((size_t)MM * NN_ * 2);
    unsigned short* Thp = (unsigned short*)alloc((size_t)2 * BB * NN_ * 2); // fp16 T partials
    // --- overlay: NS temps (dead after RT) aliased with Tp (decode partials) ---
    const size_t overlay = off;
    float* G  = (float*)alloc((size_t)NN_ * NN_ * 4);
    unsigned short* GH  = (unsigned short*)alloc((size_t)NN_ * NN_ * 2);
    unsigned short* GL  = (unsigned short*)alloc((size_t)NN_ * NN_ * 2);
    float* X0 = (float*)alloc((size_t)NN_ * NN_ * 4);
    float* X1 = (float*)alloc((size_t)NN_ * NN_ * 4);
    float* Yb = (float*)alloc((size_t)NN_ * NN_ * 4);
    unsigned short* YbH = (unsigned short*)alloc((size_t)NN_ * NN_ * 2);
    unsigned short* YbL = (unsigned short*)alloc((size_t)NN_ * NN_ * 2);
    float* rowsum = (float*)alloc(NN_ * 4);
    float* cbuf   = (float*)alloc(256);
    float* Pp = (float*)alloc((size_t)4 * NN_ * NN_ * 4);  // split-K f32 partials
    // Tp (2 x 2048x768 f32 = 12.6 MB) aliases the NS-temp region (~14.2 MB);
    // NS temps dead before first Tp use (RT GEMM f32 scratch / decode partials).
    float* Tp = (float*)(wsb + overlay);
    const size_t TPS = (size_t)BB * NN_;

    (void)hipMemsetAsync(wbuf, 0, (size_t)BB * MM * sizeof(float), stream);

    const dim3 blk(256);
    const dim3 gsk(NN_ / 64, NN_ / 64, 4);
    const int  RED = (NN_ * NN_ / 4) / 256;   // 576

    rownorm_kernel<<<MM, blk, 0, stream>>>(w, wnH, wnL, wnTH, wnTL);

    // adotb = x @ wn^T (M2048 N3072 K768); emit y2_0 = fp16(adotb)
    gemm_big<32,48,1,8,24,0,0,1,0><<<1536, blk, 0, stream>>>(
        x, nullptr, NN_, 0, wnH, wnL, NN_, adotb, MM, 0, NN_,
        nullptr, nullptr, nullptr, y2h, nullptr, nullptr);

    // G = wn^T wn + I (768x768, K=3072), split-K=4 + reduce(+I, split)
    gemm_sk<1><<<gsk, blk, 0, stream>>>(
        nullptr, wnTH, wnTL, MM, wnTH, wnTL, MM, Pp, MM / 4);
    red_ns<1><<<RED, blk, 0, stream>>>(Pp, nullptr, G, GH, GL);

    rowabs_kernel<<<NN_, blk, 0, stream>>>(G, rowsum);
    cmax_kernel<<<1, blk, 0, stream>>>(rowsum, cbuf);
    initdiag_kernel<<<(NN_ * NN_) / 256, blk, 0, stream>>>(X0, cbuf);

    // Newton-Schulz X <- 2X - XGX, 7 iterations, split-K=4 per GEMM
    float* Xc = X0;
    float* Xn = X1;
    for (int it = 0; it < 7; ++it) {
        gemm_sk<0><<<gsk, blk, 0, stream>>>(
            Xc, nullptr, nullptr, NN_, GH, GL, NN_, Pp, NN_ / 4);
        red_ns<0><<<RED, blk, 0, stream>>>(Pp, nullptr, Yb, YbH, YbL);
        gemm_sk<0><<<gsk, blk, 0, stream>>>(
            Xc, nullptr, nullptr, NN_, YbH, YbL, NN_, Pp, NN_ / 4);
        red_ns<2><<<RED, blk, 0, stream>>>(Pp, Xc, Xn, QH, QL);
        float* t = Xc; Xc = Xn; Xn = t;
    }
    // QH/QL = fp16 split of G^{-1}

    // RT = wn @ Ginv (M3072 N768 K768); emit RTH/RTL (f32 scratch to Tp)
    gemm_big<48,12,1,12,6,1,0,2,0><<<576, blk, 0, stream>>>(
        nullptr, wnH, NN_, 0, QH, QL, NN_, Tp, NN_, 0, NN_,
        nullptr, nullptr, nullptr, nullptr, RTH, RTL);

    // ADMM loop: T = y2 @ wn -> fp16 partials Thp (KS=2);
    // w-update sums the fp16 pair in its A-staging (AMODE=4)
    for (int it = 0; it < 20; ++it) {
        gemm_big<32,12,2,16,6,1,4,0,0><<<768, blk, 0, stream>>>(
            nullptr, y2h, MM, 0, wnTH, wnTL, MM, nullptr, NN_, TPS, MM / 2,
            nullptr, nullptr, nullptr, Thp, nullptr, nullptr);
        if (it < 19) {
            gemm_big<32,48,1,8,24,4,3,0,0><<<1536, blk, 0, stream>>>(
                nullptr, Thp, NN_, TPS, RTH, RTL, NN_, nullptr, MM, 0, NN_,
                adotb, wbuf, nullptr, y2h, nullptr, nullptr);
        } else {
            gemm_big<32,48,1,8,24,4,3,0,1><<<1536, blk, 0, stream>>>(
                nullptr, Thp, NN_, TPS, RTH, RTL, NN_, nullptr, MM, 0, NN_,
                adotb, wbuf, z, nullptr, nullptr, nullptr);
        }
    }

    // decoded = z @ wn (M2048 N768 K3072), KS=2 f32 partials + reduce
    gemm_big<32,12,2,16,6,0,0,0,0><<<768, blk, 0, stream>>>(
        z, nullptr, MM, 0, wnTH, wnTL, MM, Tp, NN_, TPS, MM / 2,
        nullptr, nullptr, nullptr, nullptr, nullptr, nullptr);
    add2_kernel<<<(BB * NN_ / 4) / 256, blk, 0, stream>>>(Tp, TPS, dec);
}